// Round 1
// baseline (15111.436 us; speedup 1.0000x reference)
//
#include <hip/hip_runtime.h>
#include <hip/hip_bf16.h>

#define NV 100000
#define NE 20000
#define NNZ_CNT 3200000

// ---------------- counts (once per call; shared by all 4 segment-means) ----------------
__global__ __launch_bounds__(256) void count_kernel(const int* __restrict__ vids,
                                                    const int* __restrict__ eids,
                                                    int* __restrict__ cntV, int* __restrict__ cntE,
                                                    int nnz) {
    int i = blockIdx.x * 256 + threadIdx.x;
    if (i < nnz) {
        atomicAdd(&cntV[vids[i]], 1);
        atomicAdd(&cntE[eids[i]], 1);
    }
}

// ---------------- A[M x 128] @ W[128 x 128] -> out[M x 128] ----------------
__global__ __launch_bounds__(256) void mm_k128_n128(const float* __restrict__ A,
                                                    const float* __restrict__ W,
                                                    float* __restrict__ out, int M) {
    __shared__ float Wl[128 * 128];   // 64 KB
    __shared__ float Al[32 * 128];    // 16 KB
    for (int i = threadIdx.x; i < 4096; i += 256)
        ((float4*)Wl)[i] = ((const float4*)W)[i];
    int row0 = blockIdx.x * 32;
    for (int i = threadIdx.x; i < 1024; i += 256) {
        int r = i >> 5, c4 = i & 31;
        int row = row0 + r;
        float4 v = make_float4(0.f, 0.f, 0.f, 0.f);
        if (row < M) v = ((const float4*)(A + (size_t)row * 128))[c4];
        ((float4*)Al)[i] = v;
    }
    __syncthreads();
    int cx = (threadIdx.x & 31) * 4;
    int rg = (threadIdx.x >> 5) * 4;
    float acc[4][4] = {};
#pragma unroll 8
    for (int k = 0; k < 128; ++k) {
        float4 w = *(const float4*)&Wl[k * 128 + cx];
#pragma unroll
        for (int r = 0; r < 4; ++r) {
            float a = Al[(rg + r) * 128 + k];
            acc[r][0] = fmaf(a, w.x, acc[r][0]);
            acc[r][1] = fmaf(a, w.y, acc[r][1]);
            acc[r][2] = fmaf(a, w.z, acc[r][2]);
            acc[r][3] = fmaf(a, w.w, acc[r][3]);
        }
    }
#pragma unroll
    for (int r = 0; r < 4; ++r) {
        int row = row0 + rg + r;
        if (row < M)
            *(float4*)&out[(size_t)row * 128 + cx] =
                make_float4(acc[r][0], acc[r][1], acc[r][2], acc[r][3]);
    }
}

// ---------------- A[M x 128] @ W[128 x 40] -> out[M x 40] ----------------
__global__ __launch_bounds__(256) void mm_k128_n40(const float* __restrict__ A,
                                                   const float* __restrict__ W,
                                                   float* __restrict__ out, int M) {
    __shared__ float Wl[128 * 40];    // 20 KB
    __shared__ float Al[24 * 128];    // 12 KB
    for (int i = threadIdx.x; i < 1280; i += 256)
        ((float4*)Wl)[i] = ((const float4*)W)[i];
    int row0 = blockIdx.x * 24;
    for (int i = threadIdx.x; i < 768; i += 256) {
        int r = i >> 5, c4 = i & 31;
        int row = row0 + r;
        float4 v = make_float4(0.f, 0.f, 0.f, 0.f);
        if (row < M) v = ((const float4*)(A + (size_t)row * 128))[c4];
        ((float4*)Al)[i] = v;
    }
    __syncthreads();
    if (threadIdx.x >= 240) return;
    int col = threadIdx.x % 40;
    int rg = (threadIdx.x / 40) * 4;
    float acc[4] = {};
#pragma unroll 8
    for (int k = 0; k < 128; ++k) {
        float w = Wl[k * 40 + col];
#pragma unroll
        for (int r = 0; r < 4; ++r)
            acc[r] = fmaf(Al[(rg + r) * 128 + k], w, acc[r]);
    }
#pragma unroll
    for (int r = 0; r < 4; ++r) {
        int row = row0 + rg + r;
        if (row < M) out[(size_t)row * 40 + col] = acc[r];
    }
}

// ---------------- A[M x 40] @ W[40 x 40] -> out[M x 40] ----------------
__global__ __launch_bounds__(256) void mm_k40_n40(const float* __restrict__ A,
                                                  const float* __restrict__ W,
                                                  float* __restrict__ out, int M) {
    __shared__ float Wl[1600];
    for (int i = threadIdx.x; i < 400; i += 256)
        ((float4*)Wl)[i] = ((const float4*)W)[i];
    __syncthreads();
    int idx = blockIdx.x * 256 + threadIdx.x;
    int row = idx / 40, col = idx % 40;
    if (row >= M) return;
    const float* a = A + (size_t)row * 40;
    float acc = 0.f;
#pragma unroll
    for (int k = 0; k < 40; ++k)
        acc = fmaf(a[k], Wl[k * 40 + col], acc);
    out[idx] = acc;
}

// ---------------- gather rows of src by sids, atomic-scatter-add into acc by dids ----------------
template <int C4>
__global__ __launch_bounds__(256) void scatter_kernel(const float* __restrict__ src,
                                                      const int* __restrict__ sids,
                                                      const int* __restrict__ dids,
                                                      float* __restrict__ acc, int nnz) {
    int gid = blockIdx.x * 256 + threadIdx.x;
    int i = gid / C4, c = gid % C4;
    if (i >= nnz) return;
    int s = sids[i], d = dids[i];
    float4 v = ((const float4*)(src + (size_t)s * (C4 * 4)))[c];
    float* p = acc + (size_t)d * (C4 * 4) + c * 4;
    atomicAdd(p + 0, v.x);
    atomicAdd(p + 1, v.y);
    atomicAdd(p + 2, v.z);
    atomicAdd(p + 3, v.w);
}

// ---------------- out = relu(acc / max(cnt,1)) ----------------
template <int C4>
__global__ __launch_bounds__(256) void fin_relu(const float* __restrict__ acc,
                                                const int* __restrict__ cnt,
                                                float* __restrict__ out, int rows) {
    int idx = blockIdx.x * 256 + threadIdx.x;
    if (idx >= rows * C4) return;
    int row = idx / C4;
    int c = cnt[row];
    float n = (float)(c > 0 ? c : 1);
    float4 v = ((const float4*)acc)[idx];
    v.x = fmaxf(v.x / n, 0.f);
    v.y = fmaxf(v.y / n, 0.f);
    v.z = fmaxf(v.z / n, 0.f);
    v.w = fmaxf(v.w / n, 0.f);
    ((float4*)out)[idx] = v;
}

// ---------------- out = bn(relu(acc / max(cnt,1))), C=128 ----------------
__global__ __launch_bounds__(256) void fin_relu_bn(const float* __restrict__ acc,
                                                   const int* __restrict__ cnt,
                                                   const float* __restrict__ g,
                                                   const float* __restrict__ b,
                                                   const float* __restrict__ mu,
                                                   const float* __restrict__ var,
                                                   float* __restrict__ out, int rows) {
    int idx = blockIdx.x * 256 + threadIdx.x;
    if (idx >= rows * 32) return;
    int row = idx >> 5, c4 = idx & 31;
    int c = cnt[row];
    float n = (float)(c > 0 ? c : 1);
    float4 v = ((const float4*)acc)[idx];
    float4 gg = ((const float4*)g)[c4];
    float4 bb = ((const float4*)b)[c4];
    float4 mm = ((const float4*)mu)[c4];
    float4 vv = ((const float4*)var)[c4];
    v.x = (fmaxf(v.x / n, 0.f) - mm.x) * rsqrtf(vv.x + 1e-5f) * gg.x + bb.x;
    v.y = (fmaxf(v.y / n, 0.f) - mm.y) * rsqrtf(vv.y + 1e-5f) * gg.y + bb.y;
    v.z = (fmaxf(v.z / n, 0.f) - mm.z) * rsqrtf(vv.z + 1e-5f) * gg.z + bb.z;
    v.w = (fmaxf(v.w / n, 0.f) - mm.w) * rsqrtf(vv.w + 1e-5f) * gg.w + bb.w;
    ((float4*)out)[idx] = v;
}

// ---------------- out = log_softmax(acc / max(cnt,1)) over 40 classes, wave per row ----------------
__global__ __launch_bounds__(256) void logsoftmax_kernel(const float* __restrict__ acc,
                                                         const int* __restrict__ cnt,
                                                         float* __restrict__ out, int rows) {
    int wave = (blockIdx.x * 256 + threadIdx.x) >> 6;
    int lane = threadIdx.x & 63;
    if (wave >= rows) return;
    int c = cnt[wave];
    float n = (float)(c > 0 ? c : 1);
    float v = (lane < 40) ? acc[(size_t)wave * 40 + lane] / n : -INFINITY;
    float m = v;
#pragma unroll
    for (int o = 32; o; o >>= 1) m = fmaxf(m, __shfl_xor(m, o));
    float e = (lane < 40) ? __expf(v - m) : 0.f;
    float s = e;
#pragma unroll
    for (int o = 32; o; o >>= 1) s += __shfl_xor(s, o);
    float ls = __logf(s);
    if (lane < 40) out[(size_t)wave * 40 + lane] = v - m - ls;
}

extern "C" void kernel_launch(void* const* d_in, const int* in_sizes, int n_in,
                              void* d_out, int out_size, void* d_ws, size_t ws_size,
                              hipStream_t stream) {
    const float* x    = (const float*)d_in[0];
    const int*   vids = (const int*)d_in[1];
    const int*   eids = (const int*)d_in[2];
    const float* w1a  = (const float*)d_in[3];   // 128x128
    const float* w1b  = (const float*)d_in[4];   // 128x128
    const float* w2a  = (const float*)d_in[5];   // 128x40
    const float* w2b  = (const float*)d_in[6];   // 40x40
    const float* g    = (const float*)d_in[7];
    const float* bta  = (const float*)d_in[8];
    const float* mu   = (const float*)d_in[9];
    const float* var  = (const float*)d_in[10];
    float* out = (float*)d_out;
    char*  ws  = (char*)d_ws;

    float* buf0 = (float*)(ws);                 // V*128  (X1, then accV/X3)
    float* buf1 = (float*)(ws + 51200000);      // E*128  (accE/Y)
    float* buf2 = (float*)(ws + 61440000);      // E*128  (Y2)
    float* buf3 = (float*)(ws + 71680000);      // V*40   (X4)
    float* buf4 = (float*)(ws + 87680000);      // E*40   (accE2/Y3)
    float* buf5 = (float*)(ws + 90880000);      // E*40   (Y4)
    float* buf6 = (float*)(ws + 94080000);      // V*40   (accV2)
    int*   cntE = (int*)(ws + 110080000);       // E
    int*   cntV = (int*)(ws + 110160000);       // V      (end: 110,560,000)

    // counts (shared by all segment-means)
    hipMemsetAsync(cntE, 0, NE * 4, stream);
    hipMemsetAsync(cntV, 0, NV * 4, stream);
    count_kernel<<<(NNZ_CNT + 255) / 256, 256, 0, stream>>>(vids, eids, cntV, cntE, NNZ_CNT);

    // ---- layer 1 ----
    mm_k128_n128<<<(NV + 31) / 32, 256, 0, stream>>>(x, w1a, buf0, NV);
    hipMemsetAsync(buf1, 0, (size_t)NE * 128 * 4, stream);
    scatter_kernel<32><<<(NNZ_CNT * 32 + 255) / 256, 256, 0, stream>>>(buf0, vids, eids, buf1, NNZ_CNT);
    fin_relu<32><<<(NE * 32 + 255) / 256, 256, 0, stream>>>(buf1, cntE, buf1, NE);
    mm_k128_n128<<<(NE + 31) / 32, 256, 0, stream>>>(buf1, w1b, buf2, NE);
    hipMemsetAsync(buf0, 0, (size_t)NV * 128 * 4, stream);
    scatter_kernel<32><<<(NNZ_CNT * 32 + 255) / 256, 256, 0, stream>>>(buf2, eids, vids, buf0, NNZ_CNT);
    fin_relu_bn<<<(NV * 32 + 255) / 256, 256, 0, stream>>>(buf0, cntV, g, bta, mu, var, buf0, NV);

    // ---- layer 2 ----
    mm_k128_n40<<<(NV + 23) / 24, 256, 0, stream>>>(buf0, w2a, buf3, NV);
    hipMemsetAsync(buf4, 0, (size_t)NE * 40 * 4, stream);
    scatter_kernel<10><<<(NNZ_CNT * 10 + 255) / 256, 256, 0, stream>>>(buf3, vids, eids, buf4, NNZ_CNT);
    fin_relu<10><<<(NE * 10 + 255) / 256, 256, 0, stream>>>(buf4, cntE, buf4, NE);
    mm_k40_n40<<<(NE * 40 + 255) / 256, 256, 0, stream>>>(buf4, w2b, buf5, NE);
    hipMemsetAsync(buf6, 0, (size_t)NV * 40 * 4, stream);
    scatter_kernel<10><<<(NNZ_CNT * 10 + 255) / 256, 256, 0, stream>>>(buf5, eids, vids, buf6, NNZ_CNT);

    // ---- log_softmax (fused with /cnt) ----
    logsoftmax_kernel<<<(NV + 3) / 4, 256, 0, stream>>>(buf6, cntV, out, NV);
}

// Round 2
// 1955.886 us; speedup vs baseline: 7.7261x; 7.7261x over previous
//
#include <hip/hip_runtime.h>
#include <hip/hip_bf16.h>

#define NV 100000
#define NE 20000
#define NNZ_CNT 3200000

// ---------------- histogram of destination ids ----------------
__global__ __launch_bounds__(256) void count_kernel(const int* __restrict__ vids,
                                                    const int* __restrict__ eids,
                                                    int* __restrict__ cntV, int* __restrict__ cntE,
                                                    int nnz) {
    int i = blockIdx.x * 256 + threadIdx.x;
    if (i < nnz) {
        atomicAdd(&cntV[vids[i]], 1);
        atomicAdd(&cntE[eids[i]], 1);
    }
}

// ---------------- single-block exclusive scan: off[0..n], cur = copy of off ----------------
__global__ __launch_bounds__(1024) void scan_kernel(const int* __restrict__ cnt,
                                                    int* __restrict__ off,
                                                    int* __restrict__ cur, int n) {
    __shared__ int part[1024];
    int t = threadIdx.x;
    int per = (n + 1023) >> 10;
    int lo = t * per, hi = lo + per;
    if (hi > n) hi = n;
    int s = 0;
    for (int i = lo; i < hi; ++i) s += cnt[i];
    part[t] = s;
    __syncthreads();
    for (int o = 1; o < 1024; o <<= 1) {
        int v = (t >= o) ? part[t - o] : 0;
        __syncthreads();
        part[t] += v;
        __syncthreads();
    }
    int run = (t == 0) ? 0 : part[t - 1];
    for (int i = lo; i < hi; ++i) {
        off[i] = run; cur[i] = run;
        run += cnt[i];
    }
    if (t == 1023) off[n] = run;
}

// ---------------- counting-sort scatter of indices (CSR build) ----------------
__global__ __launch_bounds__(256) void build_kernel(const int* __restrict__ vids,
                                                    const int* __restrict__ eids,
                                                    int* __restrict__ curE, int* __restrict__ curV,
                                                    int* __restrict__ srcE, int* __restrict__ srcV,
                                                    int nnz) {
    int i = blockIdx.x * 256 + threadIdx.x;
    if (i >= nnz) return;
    int v = vids[i], e = eids[i];
    int p = atomicAdd(&curE[e], 1);
    srcE[p] = v;               // e's sources are v-rows
    int q = atomicAdd(&curV[v], 1);
    srcV[q] = e;               // v's sources are e-rows
}

// ---------------- A[M x 128] @ W[128 x 128] -> out[M x 128] ----------------
__global__ __launch_bounds__(256) void mm_k128_n128(const float* __restrict__ A,
                                                    const float* __restrict__ W,
                                                    float* __restrict__ out, int M) {
    __shared__ float Wl[128 * 128];
    __shared__ float Al[32 * 128];
    for (int i = threadIdx.x; i < 4096; i += 256)
        ((float4*)Wl)[i] = ((const float4*)W)[i];
    int row0 = blockIdx.x * 32;
    for (int i = threadIdx.x; i < 1024; i += 256) {
        int r = i >> 5, c4 = i & 31;
        int row = row0 + r;
        float4 v = make_float4(0.f, 0.f, 0.f, 0.f);
        if (row < M) v = ((const float4*)(A + (size_t)row * 128))[c4];
        ((float4*)Al)[i] = v;
    }
    __syncthreads();
    int cx = (threadIdx.x & 31) * 4;
    int rg = (threadIdx.x >> 5) * 4;
    float acc[4][4] = {};
#pragma unroll 8
    for (int k = 0; k < 128; ++k) {
        float4 w = *(const float4*)&Wl[k * 128 + cx];
#pragma unroll
        for (int r = 0; r < 4; ++r) {
            float a = Al[(rg + r) * 128 + k];
            acc[r][0] = fmaf(a, w.x, acc[r][0]);
            acc[r][1] = fmaf(a, w.y, acc[r][1]);
            acc[r][2] = fmaf(a, w.z, acc[r][2]);
            acc[r][3] = fmaf(a, w.w, acc[r][3]);
        }
    }
#pragma unroll
    for (int r = 0; r < 4; ++r) {
        int row = row0 + rg + r;
        if (row < M)
            *(float4*)&out[(size_t)row * 128 + cx] =
                make_float4(acc[r][0], acc[r][1], acc[r][2], acc[r][3]);
    }
}

// ---------------- A[M x 128] @ W[128 x 40] -> out[M x 40] ----------------
__global__ __launch_bounds__(256) void mm_k128_n40(const float* __restrict__ A,
                                                   const float* __restrict__ W,
                                                   float* __restrict__ out, int M) {
    __shared__ float Wl[128 * 40];
    __shared__ float Al[24 * 128];
    for (int i = threadIdx.x; i < 1280; i += 256)
        ((float4*)Wl)[i] = ((const float4*)W)[i];
    int row0 = blockIdx.x * 24;
    for (int i = threadIdx.x; i < 768; i += 256) {
        int r = i >> 5, c4 = i & 31;
        int row = row0 + r;
        float4 v = make_float4(0.f, 0.f, 0.f, 0.f);
        if (row < M) v = ((const float4*)(A + (size_t)row * 128))[c4];
        ((float4*)Al)[i] = v;
    }
    __syncthreads();
    if (threadIdx.x >= 240) return;
    int col = threadIdx.x % 40;
    int rg = (threadIdx.x / 40) * 4;
    float acc[4] = {};
#pragma unroll 8
    for (int k = 0; k < 128; ++k) {
        float w = Wl[k * 40 + col];
#pragma unroll
        for (int r = 0; r < 4; ++r)
            acc[r] = fmaf(Al[(rg + r) * 128 + k], w, acc[r]);
    }
#pragma unroll
    for (int r = 0; r < 4; ++r) {
        int row = row0 + rg + r;
        if (row < M) out[(size_t)row * 40 + col] = acc[r];
    }
}

// ---------------- A[M x 40] @ W[40 x 40] -> out[M x 40] ----------------
__global__ __launch_bounds__(256) void mm_k40_n40(const float* __restrict__ A,
                                                  const float* __restrict__ W,
                                                  float* __restrict__ out, int M) {
    __shared__ float Wl[1600];
    for (int i = threadIdx.x; i < 400; i += 256)
        ((float4*)Wl)[i] = ((const float4*)W)[i];
    __syncthreads();
    int idx = blockIdx.x * 256 + threadIdx.x;
    int row = idx / 40, col = idx % 40;
    if (row >= M) return;
    const float* a = A + (size_t)row * 40;
    float acc = 0.f;
#pragma unroll
    for (int k = 0; k < 40; ++k)
        acc = fmaf(a[k], Wl[k * 40 + col], acc);
    out[idx] = acc;
}

// ---------------- segment mean over 128 ch, wave per dest; MODE 0: relu, 1: relu+bn ----------------
template <int MODE>
__global__ __launch_bounds__(256) void segred128(const float* __restrict__ src,
                                                 const int* __restrict__ sidx,
                                                 const int* __restrict__ off,
                                                 float* __restrict__ out, int nDest,
                                                 const float* __restrict__ g,
                                                 const float* __restrict__ b,
                                                 const float* __restrict__ mu,
                                                 const float* __restrict__ var) {
    int wave = (blockIdx.x * 256 + threadIdx.x) >> 6;
    int lane = threadIdx.x & 63;
    if (wave >= nDest) return;
    int s0 = off[wave], s1 = off[wave + 1];
    const float* sp = src + lane * 2;
    float ax = 0.f, ay = 0.f;
    int j0 = s0;
    for (; j0 + 64 <= s1; j0 += 64) {
        int myi = sidx[j0 + lane];
#pragma unroll 8
        for (int k = 0; k < 64; ++k) {
            int r = __shfl(myi, k);
            float2 v = *(const float2*)(sp + (size_t)r * 128);
            ax += v.x; ay += v.y;
        }
    }
    if (j0 < s1) {
        int m = s1 - j0;
        int myi = (lane < m) ? sidx[j0 + lane] : 0;
        for (int k = 0; k < m; ++k) {
            int r = __shfl(myi, k);
            float2 v = *(const float2*)(sp + (size_t)r * 128);
            ax += v.x; ay += v.y;
        }
    }
    int c = s1 - s0;
    float inv = 1.f / (float)(c > 0 ? c : 1);
    ax = fmaxf(ax * inv, 0.f);
    ay = fmaxf(ay * inv, 0.f);
    if (MODE == 1) {
        int c0 = lane * 2;
        float2 gg = *(const float2*)(g + c0);
        float2 bb = *(const float2*)(b + c0);
        float2 mm = *(const float2*)(mu + c0);
        float2 vv = *(const float2*)(var + c0);
        ax = (ax - mm.x) * rsqrtf(vv.x + 1e-5f) * gg.x + bb.x;
        ay = (ay - mm.y) * rsqrtf(vv.y + 1e-5f) * gg.y + bb.y;
    }
    *(float2*)(out + (size_t)wave * 128 + lane * 2) = make_float2(ax, ay);
}

// ---------------- segment mean over 40 ch, wave per dest; MODE 0: relu, 1: log_softmax ----------------
template <int MODE>
__global__ __launch_bounds__(256) void segred40(const float* __restrict__ src,
                                                const int* __restrict__ sidx,
                                                const int* __restrict__ off,
                                                float* __restrict__ out, int nDest) {
    int wave = (blockIdx.x * 256 + threadIdx.x) >> 6;
    int lane = threadIdx.x & 63;
    if (wave >= nDest) return;
    int s0 = off[wave], s1 = off[wave + 1];
    float acc = 0.f;
    int j0 = s0;
    for (; j0 + 64 <= s1; j0 += 64) {
        int myi = sidx[j0 + lane];
#pragma unroll 8
        for (int k = 0; k < 64; ++k) {
            int r = __shfl(myi, k);
            if (lane < 40) acc += src[(size_t)r * 40 + lane];
        }
    }
    if (j0 < s1) {
        int m = s1 - j0;
        int myi = (lane < m) ? sidx[j0 + lane] : 0;
        for (int k = 0; k < m; ++k) {
            int r = __shfl(myi, k);
            if (lane < 40) acc += src[(size_t)r * 40 + lane];
        }
    }
    int c = s1 - s0;
    float inv = 1.f / (float)(c > 0 ? c : 1);
    float v = acc * inv;
    if (MODE == 0) {
        if (lane < 40) out[(size_t)wave * 40 + lane] = fmaxf(v, 0.f);
    } else {
        float mv = (lane < 40) ? v : -INFINITY;
#pragma unroll
        for (int o = 32; o; o >>= 1) mv = fmaxf(mv, __shfl_xor(mv, o));
        float e = (lane < 40) ? __expf(v - mv) : 0.f;
#pragma unroll
        for (int o = 32; o; o >>= 1) e += __shfl_xor(e, o);
        float ls = __logf(e);
        if (lane < 40) out[(size_t)wave * 40 + lane] = v - mv - ls;
    }
}

extern "C" void kernel_launch(void* const* d_in, const int* in_sizes, int n_in,
                              void* d_out, int out_size, void* d_ws, size_t ws_size,
                              hipStream_t stream) {
    const float* x    = (const float*)d_in[0];
    const int*   vids = (const int*)d_in[1];
    const int*   eids = (const int*)d_in[2];
    const float* w1a  = (const float*)d_in[3];
    const float* w1b  = (const float*)d_in[4];
    const float* w2a  = (const float*)d_in[5];
    const float* w2b  = (const float*)d_in[6];
    const float* g    = (const float*)d_in[7];
    const float* bta  = (const float*)d_in[8];
    const float* mu   = (const float*)d_in[9];
    const float* var  = (const float*)d_in[10];
    float* out = (float*)d_out;
    char*  ws  = (char*)d_ws;

    // workspace layout (bytes)
    int*   srcE = (int*)(ws);                       //  0      .. 12.8M   (nnz)
    int*   srcV = (int*)(ws + 12800000);            // 12.8M   .. 25.6M   (nnz)
    int*   cntE = (int*)(ws + 25600000);            // 80 KB
    int*   cntV = (int*)(ws + 25680000);            // 400 KB
    int*   offE = (int*)(ws + 26080000);            // 80,004 B
    int*   offV = (int*)(ws + 26161000);            // 400,004 B
    int*   curE = (int*)(ws + 26562000);            // 80 KB
    int*   curV = (int*)(ws + 26642000);            // 400 KB -> end 27,042,000
    float* buf0 = (float*)(ws + 27100000);          // V*128 = 51.2 MB  -> 78.3M
    float* bufY = (float*)(ws + 78300000);          // E*128 = 10.24 MB -> 88.54M
    float* bufY2= (float*)(ws + 88540000);          // E*128 = 10.24 MB -> 98.78M
    float* buf3 = (float*)(ws + 78300000);          // V*40 = 16 MB (reuses Y after layer 1)
    float* buf4 = (float*)(ws + 94300000);          // E*40 = 3.2 MB
    float* buf5 = (float*)(ws + 97500000);          // E*40 = 3.2 MB -> 100.7M
    // NOTE: buf3 overlaps bufY/bufY2 but only after both are dead.

    // ---- CSR build (counting sort by destination) ----
    hipMemsetAsync(cntE, 0, NE * 4, stream);
    hipMemsetAsync(cntV, 0, NV * 4, stream);
    count_kernel<<<(NNZ_CNT + 255) / 256, 256, 0, stream>>>(vids, eids, cntV, cntE, NNZ_CNT);
    scan_kernel<<<1, 1024, 0, stream>>>(cntE, offE, curE, NE);
    scan_kernel<<<1, 1024, 0, stream>>>(cntV, offV, curV, NV);
    build_kernel<<<(NNZ_CNT + 255) / 256, 256, 0, stream>>>(vids, eids, curE, curV, srcE, srcV, NNZ_CNT);

    // ---- layer 1 ----
    mm_k128_n128<<<(NV + 31) / 32, 256, 0, stream>>>(x, w1a, buf0, NV);
    segred128<0><<<(NE * 64 + 255) / 256, 256, 0, stream>>>(buf0, srcE, offE, bufY, NE,
                                                            nullptr, nullptr, nullptr, nullptr);
    mm_k128_n128<<<(NE + 31) / 32, 256, 0, stream>>>(bufY, w1b, bufY2, NE);
    segred128<1><<<(NV * 64 + 255) / 256, 256, 0, stream>>>(bufY2, srcV, offV, buf0, NV,
                                                            g, bta, mu, var);

    // ---- layer 2 ----
    mm_k128_n40<<<(NV + 23) / 24, 256, 0, stream>>>(buf0, w2a, buf3, NV);
    segred40<0><<<(NE * 64 + 255) / 256, 256, 0, stream>>>(buf3, srcE, offE, buf4, NE);
    mm_k40_n40<<<(NE * 40 + 255) / 256, 256, 0, stream>>>(buf4, w2b, buf5, NE);
    segred40<1><<<(NV * 64 + 255) / 256, 256, 0, stream>>>(buf5, srcV, offV, out, NV);
}

// Round 3
// 960.995 us; speedup vs baseline: 15.7248x; 2.0353x over previous
//
#include <hip/hip_runtime.h>
#include <hip/hip_bf16.h>

#define NV 100000
#define NE 20000
#define NNZ 3200000
#define CHUNK 4096
#define NBLK ((NNZ + CHUNK - 1) / CHUNK)   // 782
#define NBE 157   // E buckets: e>>7, e<20000
#define NBV 196   // V buckets: v>>9, v<100000

// ---------------- S1: coarse bucket histograms (hb[0..255]=E by e>>7, hb[256..511]=V by v>>9) ----
__global__ __launch_bounds__(256) void s1_hist(const int* __restrict__ vids,
                                               const int* __restrict__ eids,
                                               int* __restrict__ hb) {
    __shared__ int h[512];
    for (int i = threadIdx.x; i < 512; i += 256) h[i] = 0;
    __syncthreads();
    int base = blockIdx.x * CHUNK;
#pragma unroll
    for (int k = 0; k < 16; ++k) {
        int i = base + k * 256 + threadIdx.x;
        if (i < NNZ) {
            atomicAdd(&h[eids[i] >> 7], 1);
            atomicAdd(&h[256 + (vids[i] >> 9)], 1);
        }
    }
    __syncthreads();
    for (int i = threadIdx.x; i < 512; i += 256)
        if (h[i]) atomicAdd(&hb[i], h[i]);
}

// ---------------- S2: scan bucket histograms -> bases + cursors + sentinels ----------------
__global__ void s2_scan(const int* __restrict__ hb, int* __restrict__ bbE, int* __restrict__ bbV,
                        int* __restrict__ gcurE, int* __restrict__ gcurV,
                        int* __restrict__ offE, int* __restrict__ offV) {
    int t = threadIdx.x;
    if (t == 0) {
        int run = 0;
        for (int b = 0; b < 256; ++b) { bbE[b] = run; gcurE[b] = run; run += hb[b]; }
        bbE[256] = run; offE[NE] = run;
    } else if (t == 1) {
        int run = 0;
        for (int b = 0; b < 256; ++b) { bbV[b] = run; gcurV[b] = run; run += hb[256 + b]; }
        bbV[256] = run; offV[NV] = run;
    }
}

// ---------------- S3: binned scatter (block-level counting sort by bucket, coalesced flush) ----
__global__ __launch_bounds__(256) void s3_bin(const int* __restrict__ vids,
                                              const int* __restrict__ eids,
                                              int* __restrict__ gcurE, int* __restrict__ gcurV,
                                              unsigned* __restrict__ pkE, unsigned* __restrict__ pkV) {
    __shared__ int h[256], sc[256], gp[256];
    __shared__ unsigned staged[CHUNK];
    __shared__ unsigned char sb[CHUNK];
    int tid = threadIdx.x;
    int base = blockIdx.x * CHUNK;
    int n = NNZ - base; if (n > CHUNK) n = CHUNK;
    unsigned pe[16], pv[16];
#pragma unroll
    for (int k = 0; k < 16; ++k) {
        int i = base + k * 256 + tid;
        pe[k] = 0u; pv[k] = 0u;
        if (i < NNZ) {
            unsigned e = (unsigned)eids[i], v = (unsigned)vids[i];
            pe[k] = (e << 17) | v;        // bucket = pe>>24 == e>>7
            pv[k] = (v << 15) | e;        // bucket = pv>>24 == v>>9
        }
    }
    // ======== side E ========
    h[tid] = 0;
    __syncthreads();
#pragma unroll
    for (int k = 0; k < 16; ++k)
        if (base + k * 256 + tid < NNZ) atomicAdd(&h[pe[k] >> 24], 1);
    __syncthreads();
    if (tid == 0) { int run = 0; for (int b = 0; b < 256; ++b) { int c = h[b]; h[b] = run; sc[b] = run; run += c; } }
    __syncthreads();
#pragma unroll
    for (int k = 0; k < 16; ++k)
        if (base + k * 256 + tid < NNZ) {
            int b = pe[k] >> 24;
            int pos = atomicAdd(&h[b], 1);
            staged[pos] = pe[k]; sb[pos] = (unsigned char)b;
        }
    __syncthreads();
    { int cnt = h[tid] - sc[tid]; gp[tid] = cnt ? atomicAdd(&gcurE[tid], cnt) : 0; }
    __syncthreads();
    for (int i = tid; i < n; i += 256) {
        int b = sb[i];
        pkE[gp[b] + (i - sc[b])] = staged[i];
    }
    __syncthreads();
    // ======== side V ========
    h[tid] = 0;
    __syncthreads();
#pragma unroll
    for (int k = 0; k < 16; ++k)
        if (base + k * 256 + tid < NNZ) atomicAdd(&h[pv[k] >> 24], 1);
    __syncthreads();
    if (tid == 0) { int run = 0; for (int b = 0; b < 256; ++b) { int c = h[b]; h[b] = run; sc[b] = run; run += c; } }
    __syncthreads();
#pragma unroll
    for (int k = 0; k < 16; ++k)
        if (base + k * 256 + tid < NNZ) {
            int b = pv[k] >> 24;
            int pos = atomicAdd(&h[b], 1);
            staged[pos] = pv[k]; sb[pos] = (unsigned char)b;
        }
    __syncthreads();
    { int cnt = h[tid] - sc[tid]; gp[tid] = cnt ? atomicAdd(&gcurV[tid], cnt) : 0; }
    __syncthreads();
    for (int i = tid; i < n; i += 256) {
        int b = sb[i];
        pkV[gp[b] + (i - sc[b])] = staged[i];
    }
}

// ---------------- S4: per-bucket fine counting sort -> CSR src lists + offsets ----------------
__global__ __launch_bounds__(256) void s4_sort(const unsigned* __restrict__ pkE,
                                               const unsigned* __restrict__ pkV,
                                               const int* __restrict__ bbE, const int* __restrict__ bbV,
                                               int* __restrict__ offE, int* __restrict__ offV,
                                               int* __restrict__ srcE, int* __restrict__ srcV) {
    __shared__ int h[512];
    int blk = blockIdx.x, tid = threadIdx.x;
    bool isE = blk < NBE;
    const unsigned* pk = isE ? pkE : pkV;
    const int* bb = isE ? bbE : bbV;
    int* off = isE ? offE : offV;
    int* srcO = isE ? srcE : srcV;
    int b = isE ? blk : blk - NBE;
    int NLOC = isE ? 128 : 512;
    int SH = isE ? 17 : 15;
    int LM = NLOC - 1;
    unsigned PM = isE ? 0x1FFFFu : 0x7FFFu;
    int d0 = isE ? (b << 7) : (b << 9);
    int nD = isE ? NE : NV;
    int base = bb[b], end = bb[b + 1];
    for (int l = tid; l < NLOC; l += 256) h[l] = 0;
    __syncthreads();
    for (int i = base + tid; i < end; i += 256)
        atomicAdd(&h[(pk[i] >> SH) & LM], 1);
    __syncthreads();
    if (tid == 0) { int run = 0; for (int l = 0; l < NLOC; ++l) { int c = h[l]; h[l] = run; run += c; } }
    __syncthreads();
    for (int l = tid; l < NLOC; l += 256) { int d = d0 + l; if (d < nD) off[d] = base + h[l]; }
    __syncthreads();
    for (int i = base + tid; i < end; i += 256) {
        unsigned p = pk[i];
        int pos = atomicAdd(&h[(p >> SH) & LM], 1);
        srcO[base + pos] = (int)(p & PM);
    }
}

// ---------------- A[M x 128] @ W[128 x 128] -> out[M x 128], optional fused relu ----------------
template <bool RELU>
__global__ __launch_bounds__(256) void mm_k128_n128(const float* __restrict__ A,
                                                    const float* __restrict__ W,
                                                    float* __restrict__ out, int M) {
    __shared__ float Wl[128 * 128];
    __shared__ float Al[32 * 128];
    for (int i = threadIdx.x; i < 4096; i += 256)
        ((float4*)Wl)[i] = ((const float4*)W)[i];
    int row0 = blockIdx.x * 32;
    for (int i = threadIdx.x; i < 1024; i += 256) {
        int r = i >> 5, c4 = i & 31;
        int row = row0 + r;
        float4 v = make_float4(0.f, 0.f, 0.f, 0.f);
        if (row < M) v = ((const float4*)(A + (size_t)row * 128))[c4];
        ((float4*)Al)[i] = v;
    }
    __syncthreads();
    int cx = (threadIdx.x & 31) * 4;
    int rg = (threadIdx.x >> 5) * 4;
    float acc[4][4] = {};
#pragma unroll 8
    for (int k = 0; k < 128; ++k) {
        float4 w = *(const float4*)&Wl[k * 128 + cx];
#pragma unroll
        for (int r = 0; r < 4; ++r) {
            float a = Al[(rg + r) * 128 + k];
            acc[r][0] = fmaf(a, w.x, acc[r][0]);
            acc[r][1] = fmaf(a, w.y, acc[r][1]);
            acc[r][2] = fmaf(a, w.z, acc[r][2]);
            acc[r][3] = fmaf(a, w.w, acc[r][3]);
        }
    }
#pragma unroll
    for (int r = 0; r < 4; ++r) {
        int row = row0 + rg + r;
        if (row < M) {
            float4 o = make_float4(acc[r][0], acc[r][1], acc[r][2], acc[r][3]);
            if (RELU) {
                o.x = fmaxf(o.x, 0.f); o.y = fmaxf(o.y, 0.f);
                o.z = fmaxf(o.z, 0.f); o.w = fmaxf(o.w, 0.f);
            }
            *(float4*)&out[(size_t)row * 128 + cx] = o;
        }
    }
}

// ---------------- A[M x 128] @ W[128 x 40] -> out[M x 40] ----------------
__global__ __launch_bounds__(256) void mm_k128_n40(const float* __restrict__ A,
                                                   const float* __restrict__ W,
                                                   float* __restrict__ out, int M) {
    __shared__ float Wl[128 * 40];
    __shared__ float Al[24 * 128];
    for (int i = threadIdx.x; i < 1280; i += 256)
        ((float4*)Wl)[i] = ((const float4*)W)[i];
    int row0 = blockIdx.x * 24;
    for (int i = threadIdx.x; i < 768; i += 256) {
        int r = i >> 5, c4 = i & 31;
        int row = row0 + r;
        float4 v = make_float4(0.f, 0.f, 0.f, 0.f);
        if (row < M) v = ((const float4*)(A + (size_t)row * 128))[c4];
        ((float4*)Al)[i] = v;
    }
    __syncthreads();
    if (threadIdx.x >= 240) return;
    int col = threadIdx.x % 40;
    int rg = (threadIdx.x / 40) * 4;
    float acc[4] = {};
#pragma unroll 8
    for (int k = 0; k < 128; ++k) {
        float w = Wl[k * 40 + col];
#pragma unroll
        for (int r = 0; r < 4; ++r)
            acc[r] = fmaf(Al[(rg + r) * 128 + k], w, acc[r]);
    }
#pragma unroll
    for (int r = 0; r < 4; ++r) {
        int row = row0 + rg + r;
        if (row < M) out[(size_t)row * 40 + col] = acc[r];
    }
}

// ---------------- A[M x 40] @ W[40 x 40] -> out[M x 40] ----------------
__global__ __launch_bounds__(256) void mm_k40_n40(const float* __restrict__ A,
                                                  const float* __restrict__ W,
                                                  float* __restrict__ out, int M) {
    __shared__ float Wl[1600];
    for (int i = threadIdx.x; i < 400; i += 256)
        ((float4*)Wl)[i] = ((const float4*)W)[i];
    __syncthreads();
    int idx = blockIdx.x * 256 + threadIdx.x;
    int row = idx / 40, col = idx % 40;
    if (row >= M) return;
    const float* a = A + (size_t)row * 40;
    float acc = 0.f;
#pragma unroll
    for (int k = 0; k < 40; ++k)
        acc = fmaf(a[k], Wl[k * 40 + col], acc);
    out[idx] = acc;
}

// ---------------- segment mean over 128 ch, wave per dest; MODE 0: plain, 1: relu+bn ----------------
template <int MODE>
__global__ __launch_bounds__(256) void segred128(const float* __restrict__ src,
                                                 const int* __restrict__ sidx,
                                                 const int* __restrict__ off,
                                                 float* __restrict__ out, int nDest,
                                                 const float* __restrict__ g,
                                                 const float* __restrict__ b,
                                                 const float* __restrict__ mu,
                                                 const float* __restrict__ var) {
    int wave = (blockIdx.x * 256 + threadIdx.x) >> 6;
    int lane = threadIdx.x & 63;
    if (wave >= nDest) return;
    int s0 = off[wave], s1 = off[wave + 1];
    const float* sp = src + lane * 2;
    float ax = 0.f, ay = 0.f;
    int j0 = s0;
    for (; j0 + 64 <= s1; j0 += 64) {
        int myi = sidx[j0 + lane];
#pragma unroll 8
        for (int k = 0; k < 64; ++k) {
            int r = __shfl(myi, k);
            float2 v = *(const float2*)(sp + (size_t)r * 128);
            ax += v.x; ay += v.y;
        }
    }
    if (j0 < s1) {
        int m = s1 - j0;
        int myi = (lane < m) ? sidx[j0 + lane] : 0;
        for (int k = 0; k < m; ++k) {
            int r = __shfl(myi, k);
            float2 v = *(const float2*)(sp + (size_t)r * 128);
            ax += v.x; ay += v.y;
        }
    }
    int c = s1 - s0;
    float inv = 1.f / (float)(c > 0 ? c : 1);
    ax = ax * inv;
    ay = ay * inv;
    if (MODE == 1) {
        ax = fmaxf(ax, 0.f); ay = fmaxf(ay, 0.f);
        int c0 = lane * 2;
        float2 gg = *(const float2*)(g + c0);
        float2 bb = *(const float2*)(b + c0);
        float2 mm = *(const float2*)(mu + c0);
        float2 vv = *(const float2*)(var + c0);
        ax = (ax - mm.x) * rsqrtf(vv.x + 1e-5f) * gg.x + bb.x;
        ay = (ay - mm.y) * rsqrtf(vv.y + 1e-5f) * gg.y + bb.y;
    }
    *(float2*)(out + (size_t)wave * 128 + lane * 2) = make_float2(ax, ay);
}

// ---------------- segment mean over 40 ch, wave per dest; MODE 0: relu, 1: log_softmax ----------------
template <int MODE>
__global__ __launch_bounds__(256) void segred40(const float* __restrict__ src,
                                                const int* __restrict__ sidx,
                                                const int* __restrict__ off,
                                                float* __restrict__ out, int nDest) {
    int wave = (blockIdx.x * 256 + threadIdx.x) >> 6;
    int lane = threadIdx.x & 63;
    if (wave >= nDest) return;
    int s0 = off[wave], s1 = off[wave + 1];
    float acc = 0.f;
    int j0 = s0;
    for (; j0 + 64 <= s1; j0 += 64) {
        int myi = sidx[j0 + lane];
#pragma unroll 8
        for (int k = 0; k < 64; ++k) {
            int r = __shfl(myi, k);
            if (lane < 40) acc += src[(size_t)r * 40 + lane];
        }
    }
    if (j0 < s1) {
        int m = s1 - j0;
        int myi = (lane < m) ? sidx[j0 + lane] : 0;
        for (int k = 0; k < m; ++k) {
            int r = __shfl(myi, k);
            if (lane < 40) acc += src[(size_t)r * 40 + lane];
        }
    }
    int c = s1 - s0;
    float inv = 1.f / (float)(c > 0 ? c : 1);
    float v = acc * inv;
    if (MODE == 0) {
        if (lane < 40) out[(size_t)wave * 40 + lane] = fmaxf(v, 0.f);
    } else {
        float mv = (lane < 40) ? v : -INFINITY;
#pragma unroll
        for (int o = 32; o; o >>= 1) mv = fmaxf(mv, __shfl_xor(mv, o));
        float e = (lane < 40) ? __expf(v - mv) : 0.f;
#pragma unroll
        for (int o = 32; o; o >>= 1) e += __shfl_xor(e, o);
        float ls = __logf(e);
        if (lane < 40) out[(size_t)wave * 40 + lane] = v - mv - ls;
    }
}

extern "C" void kernel_launch(void* const* d_in, const int* in_sizes, int n_in,
                              void* d_out, int out_size, void* d_ws, size_t ws_size,
                              hipStream_t stream) {
    const float* x    = (const float*)d_in[0];
    const int*   vids = (const int*)d_in[1];
    const int*   eids = (const int*)d_in[2];
    const float* w1a  = (const float*)d_in[3];
    const float* w1b  = (const float*)d_in[4];
    const float* w2a  = (const float*)d_in[5];
    const float* w2b  = (const float*)d_in[6];
    const float* g    = (const float*)d_in[7];
    const float* bta  = (const float*)d_in[8];
    const float* mu   = (const float*)d_in[9];
    const float* var  = (const float*)d_in[10];
    float* out = (float*)d_out;
    char*  ws  = (char*)d_ws;

    // ---- workspace layout (peak ~100.4 MB; round-1's 110.5 MB layout was accepted) ----
    int*      srcE = (int*)(ws);                         // 12.8 MB, live all call
    int*      srcV = (int*)(ws + 12800000);              // 12.8 MB, live all call
    unsigned* pkE  = (unsigned*)(ws + 25600000);         // 12.8 MB, dead after s4
    unsigned* pkV  = (unsigned*)(ws + 38400000);         // 12.8 MB, dead after s4
    float*    mE   = (float*)(ws + 25600000);            // E*128 (10.24 MB), after sort
    float*    y    = (float*)(ws + 38400000);            // E*128, after sort
    float*    y2   = (float*)(ws + 25600000);            // E*128, overlays mE (dead)
    float*    h    = (float*)(ws + 48640000);            // V*128 (51.2 MB) -> 99.84 MB
    float*    x4   = (float*)(ws + 25600000);            // V*40 (16 MB), overlays y2/y (dead)
    float*    y3   = (float*)(ws + 41600000);            // E*40 (3.2 MB)
    float*    y4   = (float*)(ws + 44800000);            // E*40 (3.2 MB)
    int*      offE = (int*)(ws + 99840000);              // NE+1
    int*      offV = (int*)(ws + 99921024);              // NV+1
    int*      bbE  = (int*)(ws + 100322048);             // 257
    int*      bbV  = (int*)(ws + 100323328);             // 257
    int*      gcE  = (int*)(ws + 100324608);             // 256
    int*      gcV  = (int*)(ws + 100325888);             // 256
    int*      hb   = (int*)(ws + 100327168);             // 512 -> end ~100.33 MB

    // ---- CSR build: hierarchical multisplit (no float atomics, L2-resident scatters) ----
    hipMemsetAsync(hb, 0, 512 * 4, stream);
    s1_hist<<<NBLK, 256, 0, stream>>>(vids, eids, hb);
    s2_scan<<<1, 64, 0, stream>>>(hb, bbE, bbV, gcE, gcV, offE, offV);
    s3_bin<<<NBLK, 256, 0, stream>>>(vids, eids, gcE, gcV, pkE, pkV);
    s4_sort<<<NBE + NBV, 256, 0, stream>>>(pkE, pkV, bbE, bbV, offE, offV, srcE, srcV);

    // ---- layer 1 (linearity swap: mean first, matmuls on E rows) ----
    segred128<0><<<(NE * 64 + 255) / 256, 256, 0, stream>>>(x, srcE, offE, mE, NE,
                                                            nullptr, nullptr, nullptr, nullptr);
    mm_k128_n128<true><<<(NE + 31) / 32, 256, 0, stream>>>(mE, w1a, y, NE);   // relu fused
    mm_k128_n128<false><<<(NE + 31) / 32, 256, 0, stream>>>(y, w1b, y2, NE);
    segred128<1><<<(NV * 64 + 255) / 256, 256, 0, stream>>>(y2, srcV, offV, h, NV,
                                                            g, bta, mu, var);

    // ---- layer 2 ----
    mm_k128_n40<<<(NV + 23) / 24, 256, 0, stream>>>(h, w2a, x4, NV);
    segred40<0><<<(NE * 64 + 255) / 256, 256, 0, stream>>>(x4, srcE, offE, y3, NE);
    mm_k40_n40<<<(NE * 40 + 255) / 256, 256, 0, stream>>>(y3, w2b, y4, NE);
    segred40<1><<<(NV * 64 + 255) / 256, 256, 0, stream>>>(y4, srcV, offV, out, NV);
}

// Round 4
// 840.139 us; speedup vs baseline: 17.9868x; 1.1439x over previous
//
#include <hip/hip_runtime.h>
#include <hip/hip_bf16.h>

#define NV 100000
#define NE 20000
#define NNZ 3200000
#define CHUNK 4096
#define NBLK ((NNZ + CHUNK - 1) / CHUNK)   // 782
#define NBE 157   // E buckets: e>>7
#define NBV 196   // V buckets: v>>9

__device__ __forceinline__ unsigned short f2bf(float f) {
    unsigned u = __float_as_uint(f);
    u += 0x7fffu + ((u >> 16) & 1u);       // round-to-nearest-even
    return (unsigned short)(u >> 16);
}

// ---------------- fp32 -> bf16 bulk convert (x) ----------------
__global__ __launch_bounds__(256) void cvt_bf16(const float* __restrict__ in,
                                                unsigned short* __restrict__ outp, int n4) {
    int i = blockIdx.x * 256 + threadIdx.x;
    if (i >= n4) return;
    float4 v = ((const float4*)in)[i];
    ushort4 o;
    o.x = f2bf(v.x); o.y = f2bf(v.y); o.z = f2bf(v.z); o.w = f2bf(v.w);
    ((ushort4*)outp)[i] = o;
}

// ---------------- S1: coarse bucket histograms ----------------
__global__ __launch_bounds__(256) void s1_hist(const int* __restrict__ vids,
                                               const int* __restrict__ eids,
                                               int* __restrict__ hb) {
    __shared__ int h[512];
    for (int i = threadIdx.x; i < 512; i += 256) h[i] = 0;
    __syncthreads();
    int base = blockIdx.x * CHUNK;
#pragma unroll
    for (int k = 0; k < 16; ++k) {
        int i = base + k * 256 + threadIdx.x;
        if (i < NNZ) {
            atomicAdd(&h[eids[i] >> 7], 1);
            atomicAdd(&h[256 + (vids[i] >> 9)], 1);
        }
    }
    __syncthreads();
    for (int i = threadIdx.x; i < 512; i += 256)
        if (h[i]) atomicAdd(&hb[i], h[i]);
}

// ---------------- S2: scan bucket histograms ----------------
__global__ void s2_scan(const int* __restrict__ hb, int* __restrict__ bbE, int* __restrict__ bbV,
                        int* __restrict__ gcurE, int* __restrict__ gcurV,
                        int* __restrict__ offE, int* __restrict__ offV) {
    int t = threadIdx.x;
    if (t == 0) {
        int run = 0;
        for (int b = 0; b < 256; ++b) { bbE[b] = run; gcurE[b] = run; run += hb[b]; }
        bbE[256] = run; offE[NE] = run;
    } else if (t == 1) {
        int run = 0;
        for (int b = 0; b < 256; ++b) { bbV[b] = run; gcurV[b] = run; run += hb[256 + b]; }
        bbV[256] = run; offV[NV] = run;
    }
}

// ---------------- S3: binned scatter ----------------
__global__ __launch_bounds__(256) void s3_bin(const int* __restrict__ vids,
                                              const int* __restrict__ eids,
                                              int* __restrict__ gcurE, int* __restrict__ gcurV,
                                              unsigned* __restrict__ pkE, unsigned* __restrict__ pkV) {
    __shared__ int h[256], sc[256], gp[256];
    __shared__ unsigned staged[CHUNK];
    __shared__ unsigned char sb[CHUNK];
    int tid = threadIdx.x;
    int base = blockIdx.x * CHUNK;
    int n = NNZ - base; if (n > CHUNK) n = CHUNK;
    unsigned pe[16], pv[16];
#pragma unroll
    for (int k = 0; k < 16; ++k) {
        int i = base + k * 256 + tid;
        pe[k] = 0u; pv[k] = 0u;
        if (i < NNZ) {
            unsigned e = (unsigned)eids[i], v = (unsigned)vids[i];
            pe[k] = (e << 17) | v;
            pv[k] = (v << 15) | e;
        }
    }
    // E side
    h[tid] = 0;
    __syncthreads();
#pragma unroll
    for (int k = 0; k < 16; ++k)
        if (base + k * 256 + tid < NNZ) atomicAdd(&h[pe[k] >> 24], 1);
    __syncthreads();
    if (tid == 0) { int run = 0; for (int b = 0; b < 256; ++b) { int c = h[b]; h[b] = run; sc[b] = run; run += c; } }
    __syncthreads();
#pragma unroll
    for (int k = 0; k < 16; ++k)
        if (base + k * 256 + tid < NNZ) {
            int b = pe[k] >> 24;
            int pos = atomicAdd(&h[b], 1);
            staged[pos] = pe[k]; sb[pos] = (unsigned char)b;
        }
    __syncthreads();
    { int cnt = h[tid] - sc[tid]; gp[tid] = cnt ? atomicAdd(&gcurE[tid], cnt) : 0; }
    __syncthreads();
    for (int i = tid; i < n; i += 256) {
        int b = sb[i];
        pkE[gp[b] + (i - sc[b])] = staged[i];
    }
    __syncthreads();
    // V side
    h[tid] = 0;
    __syncthreads();
#pragma unroll
    for (int k = 0; k < 16; ++k)
        if (base + k * 256 + tid < NNZ) atomicAdd(&h[pv[k] >> 24], 1);
    __syncthreads();
    if (tid == 0) { int run = 0; for (int b = 0; b < 256; ++b) { int c = h[b]; h[b] = run; sc[b] = run; run += c; } }
    __syncthreads();
#pragma unroll
    for (int k = 0; k < 16; ++k)
        if (base + k * 256 + tid < NNZ) {
            int b = pv[k] >> 24;
            int pos = atomicAdd(&h[b], 1);
            staged[pos] = pv[k]; sb[pos] = (unsigned char)b;
        }
    __syncthreads();
    { int cnt = h[tid] - sc[tid]; gp[tid] = cnt ? atomicAdd(&gcurV[tid], cnt) : 0; }
    __syncthreads();
    for (int i = tid; i < n; i += 256) {
        int b = sb[i];
        pkV[gp[b] + (i - sc[b])] = staged[i];
    }
}

// ---------------- S4: per-bucket fine counting sort ----------------
__global__ __launch_bounds__(256) void s4_sort(const unsigned* __restrict__ pkE,
                                               const unsigned* __restrict__ pkV,
                                               const int* __restrict__ bbE, const int* __restrict__ bbV,
                                               int* __restrict__ offE, int* __restrict__ offV,
                                               int* __restrict__ srcE, int* __restrict__ srcV) {
    __shared__ int h[512];
    int blk = blockIdx.x, tid = threadIdx.x;
    bool isE = blk < NBE;
    const unsigned* pk = isE ? pkE : pkV;
    const int* bb = isE ? bbE : bbV;
    int* off = isE ? offE : offV;
    int* srcO = isE ? srcE : srcV;
    int b = isE ? blk : blk - NBE;
    int NLOC = isE ? 128 : 512;
    int SH = isE ? 17 : 15;
    int LM = NLOC - 1;
    unsigned PM = isE ? 0x1FFFFu : 0x7FFFu;
    int d0 = isE ? (b << 7) : (b << 9);
    int nD = isE ? NE : NV;
    int base = bb[b], end = bb[b + 1];
    for (int l = tid; l < NLOC; l += 256) h[l] = 0;
    __syncthreads();
    for (int i = base + tid; i < end; i += 256)
        atomicAdd(&h[(pk[i] >> SH) & LM], 1);
    __syncthreads();
    if (tid == 0) { int run = 0; for (int l = 0; l < NLOC; ++l) { int c = h[l]; h[l] = run; run += c; } }
    __syncthreads();
    for (int l = tid; l < NLOC; l += 256) { int d = d0 + l; if (d < nD) off[d] = base + h[l]; }
    __syncthreads();
    for (int i = base + tid; i < end; i += 256) {
        unsigned p = pk[i];
        int pos = atomicAdd(&h[(p >> SH) & LM], 1);
        srcO[base + pos] = (int)(p & PM);
    }
}

// ---------------- A[M x 128] @ W[128 x 128]; RELU and/or bf16 output ----------------
template <bool RELU, bool BF16OUT>
__global__ __launch_bounds__(256) void mm_k128_n128(const float* __restrict__ A,
                                                    const float* __restrict__ W,
                                                    float* __restrict__ out,
                                                    unsigned short* __restrict__ out16, int M) {
    __shared__ float Wl[128 * 128];
    __shared__ float Al[32 * 128];
    for (int i = threadIdx.x; i < 4096; i += 256)
        ((float4*)Wl)[i] = ((const float4*)W)[i];
    int row0 = blockIdx.x * 32;
    for (int i = threadIdx.x; i < 1024; i += 256) {
        int r = i >> 5, c4 = i & 31;
        int row = row0 + r;
        float4 v = make_float4(0.f, 0.f, 0.f, 0.f);
        if (row < M) v = ((const float4*)(A + (size_t)row * 128))[c4];
        ((float4*)Al)[i] = v;
    }
    __syncthreads();
    int cx = (threadIdx.x & 31) * 4;
    int rg = (threadIdx.x >> 5) * 4;
    float acc[4][4] = {};
#pragma unroll 8
    for (int k = 0; k < 128; ++k) {
        float4 w = *(const float4*)&Wl[k * 128 + cx];
#pragma unroll
        for (int r = 0; r < 4; ++r) {
            float a = Al[(rg + r) * 128 + k];
            acc[r][0] = fmaf(a, w.x, acc[r][0]);
            acc[r][1] = fmaf(a, w.y, acc[r][1]);
            acc[r][2] = fmaf(a, w.z, acc[r][2]);
            acc[r][3] = fmaf(a, w.w, acc[r][3]);
        }
    }
#pragma unroll
    for (int r = 0; r < 4; ++r) {
        int row = row0 + rg + r;
        if (row < M) {
            float4 o = make_float4(acc[r][0], acc[r][1], acc[r][2], acc[r][3]);
            if (RELU) {
                o.x = fmaxf(o.x, 0.f); o.y = fmaxf(o.y, 0.f);
                o.z = fmaxf(o.z, 0.f); o.w = fmaxf(o.w, 0.f);
            }
            if (BF16OUT) {
                ushort4 u;
                u.x = f2bf(o.x); u.y = f2bf(o.y); u.z = f2bf(o.z); u.w = f2bf(o.w);
                *(ushort4*)&out16[(size_t)row * 128 + cx] = u;
            } else {
                *(float4*)&out[(size_t)row * 128 + cx] = o;
            }
        }
    }
}

// ---------------- A[M x 128] @ W[128 x 40] -> bf16 out ----------------
__global__ __launch_bounds__(256) void mm_k128_n40(const float* __restrict__ A,
                                                   const float* __restrict__ W,
                                                   unsigned short* __restrict__ out16, int M) {
    __shared__ float Wl[128 * 40];
    __shared__ float Al[24 * 128];
    for (int i = threadIdx.x; i < 1280; i += 256)
        ((float4*)Wl)[i] = ((const float4*)W)[i];
    int row0 = blockIdx.x * 24;
    for (int i = threadIdx.x; i < 768; i += 256) {
        int r = i >> 5, c4 = i & 31;
        int row = row0 + r;
        float4 v = make_float4(0.f, 0.f, 0.f, 0.f);
        if (row < M) v = ((const float4*)(A + (size_t)row * 128))[c4];
        ((float4*)Al)[i] = v;
    }
    __syncthreads();
    if (threadIdx.x >= 240) return;
    int col = threadIdx.x % 40;
    int rg = (threadIdx.x / 40) * 4;
    float acc[4] = {};
#pragma unroll 8
    for (int k = 0; k < 128; ++k) {
        float w = Wl[k * 40 + col];
#pragma unroll
        for (int r = 0; r < 4; ++r)
            acc[r] = fmaf(Al[(rg + r) * 128 + k], w, acc[r]);
    }
#pragma unroll
    for (int r = 0; r < 4; ++r) {
        int row = row0 + rg + r;
        if (row < M) out16[(size_t)row * 40 + col] = f2bf(acc[r]);
    }
}

// ---------------- A[M x 40] @ W[40 x 40] -> bf16 out ----------------
__global__ __launch_bounds__(256) void mm_k40_n40(const float* __restrict__ A,
                                                  const float* __restrict__ W,
                                                  unsigned short* __restrict__ out16, int M) {
    __shared__ float Wl[1600];
    for (int i = threadIdx.x; i < 400; i += 256)
        ((float4*)Wl)[i] = ((const float4*)W)[i];
    __syncthreads();
    int idx = blockIdx.x * 256 + threadIdx.x;
    int row = idx / 40, col = idx % 40;
    if (row >= M) return;
    const float* a = A + (size_t)row * 40;
    float acc = 0.f;
#pragma unroll
    for (int k = 0; k < 40; ++k)
        acc = fmaf(a[k], Wl[k * 40 + col], acc);
    out16[idx] = f2bf(acc);
}

// ---------------- segment mean over 128 bf16 ch, wave per dest; MODE 0: plain, 1: relu+bn ----
template <int MODE>
__global__ __launch_bounds__(256) void segred128h(const unsigned short* __restrict__ src,
                                                  const int* __restrict__ sidx,
                                                  const int* __restrict__ off,
                                                  float* __restrict__ out, int nDest,
                                                  const float* __restrict__ g,
                                                  const float* __restrict__ b,
                                                  const float* __restrict__ mu,
                                                  const float* __restrict__ var) {
    int wave = (blockIdx.x * 256 + threadIdx.x) >> 6;
    int lane = threadIdx.x & 63;
    if (wave >= nDest) return;
    int s0 = off[wave], s1 = off[wave + 1];
    const unsigned short* sp = src + lane * 2;
    float ax = 0.f, ay = 0.f;
    int j0 = s0;
    for (; j0 + 64 <= s1; j0 += 64) {
        int myi = sidx[j0 + lane];
#pragma unroll 8
        for (int k = 0; k < 64; ++k) {
            int r = __shfl(myi, k);
            unsigned u = *(const unsigned*)(sp + (size_t)r * 128);
            ax += __uint_as_float(u << 16);
            ay += __uint_as_float(u & 0xffff0000u);
        }
    }
    if (j0 < s1) {
        int m = s1 - j0;
        int myi = (lane < m) ? sidx[j0 + lane] : 0;
        for (int k = 0; k < m; ++k) {
            int r = __shfl(myi, k);
            unsigned u = *(const unsigned*)(sp + (size_t)r * 128);
            ax += __uint_as_float(u << 16);
            ay += __uint_as_float(u & 0xffff0000u);
        }
    }
    int c = s1 - s0;
    float inv = 1.f / (float)(c > 0 ? c : 1);
    ax *= inv; ay *= inv;
    if (MODE == 1) {
        ax = fmaxf(ax, 0.f); ay = fmaxf(ay, 0.f);
        int c0 = lane * 2;
        float2 gg = *(const float2*)(g + c0);
        float2 bb = *(const float2*)(b + c0);
        float2 mm = *(const float2*)(mu + c0);
        float2 vv = *(const float2*)(var + c0);
        ax = (ax - mm.x) * rsqrtf(vv.x + 1e-5f) * gg.x + bb.x;
        ay = (ay - mm.y) * rsqrtf(vv.y + 1e-5f) * gg.y + bb.y;
    }
    *(float2*)(out + (size_t)wave * 128 + lane * 2) = make_float2(ax, ay);
}

// ---------------- segment mean over 40 bf16 ch (lanes 0..19 x 2ch); MODE 0: relu, 1: log_softmax ----
template <int MODE>
__global__ __launch_bounds__(256) void segred40h(const unsigned short* __restrict__ src,
                                                 const int* __restrict__ sidx,
                                                 const int* __restrict__ off,
                                                 float* __restrict__ out, int nDest) {
    int wave = (blockIdx.x * 256 + threadIdx.x) >> 6;
    int lane = threadIdx.x & 63;
    if (wave >= nDest) return;
    int s0 = off[wave], s1 = off[wave + 1];
    bool act = lane < 20;
    const unsigned short* sp = src + lane * 2;
    float ax = 0.f, ay = 0.f;
    int j0 = s0;
    for (; j0 + 64 <= s1; j0 += 64) {
        int myi = sidx[j0 + lane];
#pragma unroll 8
        for (int k = 0; k < 64; ++k) {
            int r = __shfl(myi, k);
            if (act) {
                unsigned u = *(const unsigned*)(sp + (size_t)r * 40);
                ax += __uint_as_float(u << 16);
                ay += __uint_as_float(u & 0xffff0000u);
            }
        }
    }
    if (j0 < s1) {
        int m = s1 - j0;
        int myi = (lane < m) ? sidx[j0 + lane] : 0;
        for (int k = 0; k < m; ++k) {
            int r = __shfl(myi, k);
            if (act) {
                unsigned u = *(const unsigned*)(sp + (size_t)r * 40);
                ax += __uint_as_float(u << 16);
                ay += __uint_as_float(u & 0xffff0000u);
            }
        }
    }
    int c = s1 - s0;
    float inv = 1.f / (float)(c > 0 ? c : 1);
    ax *= inv; ay *= inv;
    if (MODE == 0) {
        if (act)
            *(float2*)(out + (size_t)wave * 40 + lane * 2) = make_float2(fmaxf(ax, 0.f), fmaxf(ay, 0.f));
    } else {
        float mv = act ? fmaxf(ax, ay) : -INFINITY;
#pragma unroll
        for (int o = 32; o; o >>= 1) mv = fmaxf(mv, __shfl_xor(mv, o));
        float e = act ? (__expf(ax - mv) + __expf(ay - mv)) : 0.f;
#pragma unroll
        for (int o = 32; o; o >>= 1) e += __shfl_xor(e, o);
        float ls = __logf(e);
        if (act)
            *(float2*)(out + (size_t)wave * 40 + lane * 2) = make_float2(ax - mv - ls, ay - mv - ls);
    }
}

extern "C" void kernel_launch(void* const* d_in, const int* in_sizes, int n_in,
                              void* d_out, int out_size, void* d_ws, size_t ws_size,
                              hipStream_t stream) {
    const float* x    = (const float*)d_in[0];
    const int*   vids = (const int*)d_in[1];
    const int*   eids = (const int*)d_in[2];
    const float* w1a  = (const float*)d_in[3];
    const float* w1b  = (const float*)d_in[4];
    const float* w2a  = (const float*)d_in[5];
    const float* w2b  = (const float*)d_in[6];
    const float* g    = (const float*)d_in[7];
    const float* bta  = (const float*)d_in[8];
    const float* mu   = (const float*)d_in[9];
    const float* var  = (const float*)d_in[10];
    float* out = (float*)d_out;
    char*  ws  = (char*)d_ws;

    // ---- workspace layout (peak ~103 MB) ----
    int*            srcE = (int*)(ws);                    // 12.8 MB, live all call
    int*            srcV = (int*)(ws + 12800000);         // 12.8 MB, live all call
    unsigned*       pkE  = (unsigned*)(ws + 25600000);    // 12.8 MB, dead after s4
    unsigned*       pkV  = (unsigned*)(ws + 38400000);    // 12.8 MB, dead after s4
    unsigned short* xh   = (unsigned short*)(ws + 51200000); // V*128 bf16 = 25.6 MB, dead after segred<0>
    float*          h    = (float*)(ws + 25600000);       // V*128 f32 = 51.2 MB (25.6-76.8, overlays pk/xh, all dead)
    float*          mE   = (float*)(ws + 76800000);       // E*128 f32 = 10.24 MB (76.8-87.04)
    float*          y    = (float*)(ws + 87040000);       // E*128 f32 = 10.24 MB (87.04-97.28)
    unsigned short* y2h  = (unsigned short*)(ws + 97280000); // E*128 bf16 = 5.12 MB (97.28-102.4)
    unsigned short* x4h  = (unsigned short*)(ws + 76800000); // V*40 bf16 = 8 MB (overlays mE, dead)
    float*          y3   = (float*)(ws + 84800000);       // E*40 f32 = 3.2 MB (84.8-88.0, overlays y head, dead)
    unsigned short* y4h  = (unsigned short*)(ws + 88000000); // E*40 bf16 = 1.6 MB (88.0-89.6)
    int*            offE = (int*)(ws + 102400000);        // NE+1
    int*            offV = (int*)(ws + 102481024);        // NV+1
    int*            bbE  = (int*)(ws + 102882048);        // 257
    int*            bbV  = (int*)(ws + 102883328);        // 257
    int*            gcE  = (int*)(ws + 102884608);        // 256
    int*            gcV  = (int*)(ws + 102885888);        // 256
    int*            hb   = (int*)(ws + 102887168);        // 512 -> end ~102.89 MB

    // ---- CSR build + x->bf16 ----
    hipMemsetAsync(hb, 0, 512 * 4, stream);
    cvt_bf16<<<(NV * 32 + 255) / 256, 256, 0, stream>>>(x, xh, NV * 32);
    s1_hist<<<NBLK, 256, 0, stream>>>(vids, eids, hb);
    s2_scan<<<1, 64, 0, stream>>>(hb, bbE, bbV, gcE, gcV, offE, offV);
    s3_bin<<<NBLK, 256, 0, stream>>>(vids, eids, gcE, gcV, pkE, pkV);
    s4_sort<<<NBE + NBV, 256, 0, stream>>>(pkE, pkV, bbE, bbV, offE, offV, srcE, srcV);

    // ---- layer 1 (mean first; matmuls on E rows) ----
    segred128h<0><<<(NE * 64 + 255) / 256, 256, 0, stream>>>(xh, srcE, offE, mE, NE,
                                                             nullptr, nullptr, nullptr, nullptr);
    mm_k128_n128<true, false><<<(NE + 31) / 32, 256, 0, stream>>>(mE, w1a, y, nullptr, NE);
    mm_k128_n128<false, true><<<(NE + 31) / 32, 256, 0, stream>>>(y, w1b, nullptr, y2h, NE);
    segred128h<1><<<(NV * 64 + 255) / 256, 256, 0, stream>>>(y2h, srcV, offV, h, NV,
                                                             g, bta, mu, var);

    // ---- layer 2 ----
    mm_k128_n40<<<(NV + 23) / 24, 256, 0, stream>>>(h, w2a, x4h, NV);
    segred40h<0><<<(NE * 64 + 255) / 256, 256, 0, stream>>>(x4h, srcE, offE, y3, NE);
    mm_k40_n40<<<(NE * 40 + 255) / 256, 256, 0, stream>>>(y3, w2b, y4h, NE);
    segred40h<1><<<(NV * 64 + 255) / 256, 256, 0, stream>>>(y4h, srcV, offV, out, NV);
}

// Round 5
// 575.925 us; speedup vs baseline: 26.2385x; 1.4588x over previous
//
#include <hip/hip_runtime.h>
#include <hip/hip_bf16.h>

#define NV 100000
#define NE 20000
#define NNZ 3200000
#define CHUNK 4096
#define NBLK ((NNZ + CHUNK - 1) / CHUNK)   // 782
#define NBE 157   // E buckets: e>>7
#define NBV 196   // V buckets: v>>9

__device__ __forceinline__ unsigned short f2bf(float f) {
    unsigned u = __float_as_uint(f);
    u += 0x7fffu + ((u >> 16) & 1u);       // round-to-nearest-even
    return (unsigned short)(u >> 16);
}
__device__ __forceinline__ float2 bfu(unsigned u) {
    return make_float2(__uint_as_float(u << 16), __uint_as_float(u & 0xffff0000u));
}

// ---------------- fp32 -> bf16 bulk convert ----------------
__global__ __launch_bounds__(256) void cvt_bf16(const float* __restrict__ in,
                                                unsigned short* __restrict__ outp, int n4) {
    int i = blockIdx.x * 256 + threadIdx.x;
    if (i >= n4) return;
    float4 v = ((const float4*)in)[i];
    ushort4 o;
    o.x = f2bf(v.x); o.y = f2bf(v.y); o.z = f2bf(v.z); o.w = f2bf(v.w);
    ((ushort4*)outp)[i] = o;
}

// ---------------- S1: coarse bucket histograms ----------------
__global__ __launch_bounds__(256) void s1_hist(const int* __restrict__ vids,
                                               const int* __restrict__ eids,
                                               int* __restrict__ hb) {
    __shared__ int h[512];
    for (int i = threadIdx.x; i < 512; i += 256) h[i] = 0;
    __syncthreads();
    int base = blockIdx.x * CHUNK;
#pragma unroll
    for (int k = 0; k < 16; ++k) {
        int i = base + k * 256 + threadIdx.x;
        if (i < NNZ) {
            atomicAdd(&h[eids[i] >> 7], 1);
            atomicAdd(&h[256 + (vids[i] >> 9)], 1);
        }
    }
    __syncthreads();
    for (int i = threadIdx.x; i < 512; i += 256)
        if (h[i]) atomicAdd(&hb[i], h[i]);
}

// ---------------- S2: scan bucket histograms ----------------
__global__ void s2_scan(const int* __restrict__ hb, int* __restrict__ bbE, int* __restrict__ bbV,
                        int* __restrict__ gcurE, int* __restrict__ gcurV,
                        int* __restrict__ offE, int* __restrict__ offV) {
    int t = threadIdx.x;
    if (t == 0) {
        int run = 0;
        for (int b = 0; b < 256; ++b) { bbE[b] = run; gcurE[b] = run; run += hb[b]; }
        bbE[256] = run; offE[NE] = run;
    } else if (t == 1) {
        int run = 0;
        for (int b = 0; b < 256; ++b) { bbV[b] = run; gcurV[b] = run; run += hb[256 + b]; }
        bbV[256] = run; offV[NV] = run;
    }
}

// ---------------- S3: binned scatter ----------------
__global__ __launch_bounds__(256) void s3_bin(const int* __restrict__ vids,
                                              const int* __restrict__ eids,
                                              int* __restrict__ gcurE, int* __restrict__ gcurV,
                                              unsigned* __restrict__ pkE, unsigned* __restrict__ pkV) {
    __shared__ int h[256], sc[256], gp[256];
    __shared__ unsigned staged[CHUNK];
    __shared__ unsigned char sb[CHUNK];
    int tid = threadIdx.x;
    int base = blockIdx.x * CHUNK;
    int n = NNZ - base; if (n > CHUNK) n = CHUNK;
    unsigned pe[16], pv[16];
#pragma unroll
    for (int k = 0; k < 16; ++k) {
        int i = base + k * 256 + tid;
        pe[k] = 0u; pv[k] = 0u;
        if (i < NNZ) {
            unsigned e = (unsigned)eids[i], v = (unsigned)vids[i];
            pe[k] = (e << 17) | v;
            pv[k] = (v << 15) | e;
        }
    }
    // E side
    h[tid] = 0;
    __syncthreads();
#pragma unroll
    for (int k = 0; k < 16; ++k)
        if (base + k * 256 + tid < NNZ) atomicAdd(&h[pe[k] >> 24], 1);
    __syncthreads();
    if (tid == 0) { int run = 0; for (int b = 0; b < 256; ++b) { int c = h[b]; h[b] = run; sc[b] = run; run += c; } }
    __syncthreads();
#pragma unroll
    for (int k = 0; k < 16; ++k)
        if (base + k * 256 + tid < NNZ) {
            int b = pe[k] >> 24;
            int pos = atomicAdd(&h[b], 1);
            staged[pos] = pe[k]; sb[pos] = (unsigned char)b;
        }
    __syncthreads();
    { int cnt = h[tid] - sc[tid]; gp[tid] = cnt ? atomicAdd(&gcurE[tid], cnt) : 0; }
    __syncthreads();
    for (int i = tid; i < n; i += 256) {
        int b = sb[i];
        pkE[gp[b] + (i - sc[b])] = staged[i];
    }
    __syncthreads();
    // V side
    h[tid] = 0;
    __syncthreads();
#pragma unroll
    for (int k = 0; k < 16; ++k)
        if (base + k * 256 + tid < NNZ) atomicAdd(&h[pv[k] >> 24], 1);
    __syncthreads();
    if (tid == 0) { int run = 0; for (int b = 0; b < 256; ++b) { int c = h[b]; h[b] = run; sc[b] = run; run += c; } }
    __syncthreads();
#pragma unroll
    for (int k = 0; k < 16; ++k)
        if (base + k * 256 + tid < NNZ) {
            int b = pv[k] >> 24;
            int pos = atomicAdd(&h[b], 1);
            staged[pos] = pv[k]; sb[pos] = (unsigned char)b;
        }
    __syncthreads();
    { int cnt = h[tid] - sc[tid]; gp[tid] = cnt ? atomicAdd(&gcurV[tid], cnt) : 0; }
    __syncthreads();
    for (int i = tid; i < n; i += 256) {
        int b = sb[i];
        pkV[gp[b] + (i - sc[b])] = staged[i];
    }
}

// ---------------- S4: per-bucket fine counting sort ----------------
__global__ __launch_bounds__(256) void s4_sort(const unsigned* __restrict__ pkE,
                                               const unsigned* __restrict__ pkV,
                                               const int* __restrict__ bbE, const int* __restrict__ bbV,
                                               int* __restrict__ offE, int* __restrict__ offV,
                                               int* __restrict__ srcE, int* __restrict__ srcV) {
    __shared__ int h[512];
    int blk = blockIdx.x, tid = threadIdx.x;
    bool isE = blk < NBE;
    const unsigned* pk = isE ? pkE : pkV;
    const int* bb = isE ? bbE : bbV;
    int* off = isE ? offE : offV;
    int* srcO = isE ? srcE : srcV;
    int b = isE ? blk : blk - NBE;
    int NLOC = isE ? 128 : 512;
    int SH = isE ? 17 : 15;
    int LM = NLOC - 1;
    unsigned PM = isE ? 0x1FFFFu : 0x7FFFu;
    int d0 = isE ? (b << 7) : (b << 9);
    int nD = isE ? NE : NV;
    int base = bb[b], end = bb[b + 1];
    for (int l = tid; l < NLOC; l += 256) h[l] = 0;
    __syncthreads();
    for (int i = base + tid; i < end; i += 256)
        atomicAdd(&h[(pk[i] >> SH) & LM], 1);
    __syncthreads();
    if (tid == 0) { int run = 0; for (int l = 0; l < NLOC; ++l) { int c = h[l]; h[l] = run; run += c; } }
    __syncthreads();
    for (int l = tid; l < NLOC; l += 256) { int d = d0 + l; if (d < nD) off[d] = base + h[l]; }
    __syncthreads();
    for (int i = base + tid; i < end; i += 256) {
        unsigned p = pk[i];
        int pos = atomicAdd(&h[(p >> SH) & LM], 1);
        srcO[base + pos] = (int)(p & PM);
    }
}

// ---------------- A[M x 128] @ W[128 x 128]; RELU and/or bf16 output ----------------
template <bool RELU, bool BF16OUT>
__global__ __launch_bounds__(256) void mm_k128_n128(const float* __restrict__ A,
                                                    const float* __restrict__ W,
                                                    float* __restrict__ out,
                                                    unsigned short* __restrict__ out16, int M) {
    __shared__ float Wl[128 * 128];
    __shared__ float Al[32 * 128];
    for (int i = threadIdx.x; i < 4096; i += 256)
        ((float4*)Wl)[i] = ((const float4*)W)[i];
    int row0 = blockIdx.x * 32;
    for (int i = threadIdx.x; i < 1024; i += 256) {
        int r = i >> 5, c4 = i & 31;
        int row = row0 + r;
        float4 v = make_float4(0.f, 0.f, 0.f, 0.f);
        if (row < M) v = ((const float4*)(A + (size_t)row * 128))[c4];
        ((float4*)Al)[i] = v;
    }
    __syncthreads();
    int cx = (threadIdx.x & 31) * 4;
    int rg = (threadIdx.x >> 5) * 4;
    float acc[4][4] = {};
#pragma unroll 8
    for (int k = 0; k < 128; ++k) {
        float4 w = *(const float4*)&Wl[k * 128 + cx];
#pragma unroll
        for (int r = 0; r < 4; ++r) {
            float a = Al[(rg + r) * 128 + k];
            acc[r][0] = fmaf(a, w.x, acc[r][0]);
            acc[r][1] = fmaf(a, w.y, acc[r][1]);
            acc[r][2] = fmaf(a, w.z, acc[r][2]);
            acc[r][3] = fmaf(a, w.w, acc[r][3]);
        }
    }
#pragma unroll
    for (int r = 0; r < 4; ++r) {
        int row = row0 + rg + r;
        if (row < M) {
            float4 o = make_float4(acc[r][0], acc[r][1], acc[r][2], acc[r][3]);
            if (RELU) {
                o.x = fmaxf(o.x, 0.f); o.y = fmaxf(o.y, 0.f);
                o.z = fmaxf(o.z, 0.f); o.w = fmaxf(o.w, 0.f);
            }
            if (BF16OUT) {
                ushort4 u;
                u.x = f2bf(o.x); u.y = f2bf(o.y); u.z = f2bf(o.z); u.w = f2bf(o.w);
                *(ushort4*)&out16[(size_t)row * 128 + cx] = u;
            } else {
                *(float4*)&out[(size_t)row * 128 + cx] = o;
            }
        }
    }
}

// ---------------- A[M x 128] @ W[128 x 40] -> relu -> f32 out ----------------
__global__ __launch_bounds__(256) void mm_k128_n40(const float* __restrict__ A,
                                                   const float* __restrict__ W,
                                                   float* __restrict__ out, int M) {
    __shared__ float Wl[128 * 40];
    __shared__ float Al[24 * 128];
    for (int i = threadIdx.x; i < 1280; i += 256)
        ((float4*)Wl)[i] = ((const float4*)W)[i];
    int row0 = blockIdx.x * 24;
    for (int i = threadIdx.x; i < 768; i += 256) {
        int r = i >> 5, c4 = i & 31;
        int row = row0 + r;
        float4 v = make_float4(0.f, 0.f, 0.f, 0.f);
        if (row < M) v = ((const float4*)(A + (size_t)row * 128))[c4];
        ((float4*)Al)[i] = v;
    }
    __syncthreads();
    if (threadIdx.x >= 240) return;
    int col = threadIdx.x % 40;
    int rg = (threadIdx.x / 40) * 4;
    float acc[4] = {};
#pragma unroll 8
    for (int k = 0; k < 128; ++k) {
        float w = Wl[k * 40 + col];
#pragma unroll
        for (int r = 0; r < 4; ++r)
            acc[r] = fmaf(Al[(rg + r) * 128 + k], w, acc[r]);
    }
#pragma unroll
    for (int r = 0; r < 4; ++r) {
        int row = row0 + rg + r;
        if (row < M) out[(size_t)row * 40 + col] = fmaxf(acc[r], 0.f);
    }
}

// ---------------- A[M x 40] @ W[40 x 40] -> bf16 out ----------------
__global__ __launch_bounds__(256) void mm_k40_n40(const float* __restrict__ A,
                                                  const float* __restrict__ W,
                                                  unsigned short* __restrict__ out16, int M) {
    __shared__ float Wl[1600];
    for (int i = threadIdx.x; i < 400; i += 256)
        ((float4*)Wl)[i] = ((const float4*)W)[i];
    __syncthreads();
    int idx = blockIdx.x * 256 + threadIdx.x;
    int row = idx / 40, col = idx % 40;
    if (row >= M) return;
    const float* a = A + (size_t)row * 40;
    float acc = 0.f;
#pragma unroll
    for (int k = 0; k < 40; ++k)
        acc = fmaf(a[k], Wl[k * 40 + col], acc);
    out16[idx] = f2bf(acc);
}

// ============ segment-mean, 128 bf16 ch, 16-lane groups (4 rows / load) ============
// MODE 0: plain -> f32 out. MODE 1: relu+bn -> bf16 out.
template <int MODE>
__global__ __launch_bounds__(256) void segred128g(const unsigned short* __restrict__ src,
                                                  const int* __restrict__ sidx,
                                                  const int* __restrict__ off,
                                                  float* __restrict__ outf,
                                                  unsigned short* __restrict__ out16,
                                                  int nDest,
                                                  const float* __restrict__ g,
                                                  const float* __restrict__ b,
                                                  const float* __restrict__ mu,
                                                  const float* __restrict__ var) {
    int wave = blockIdx.x * 4 + (threadIdx.x >> 6);
    if (wave >= nDest) return;
    int lane = threadIdx.x & 63;
    int grp = lane >> 4, li = lane & 15;
    int s0 = off[wave], s1 = off[wave + 1];
    const unsigned short* sp = src + (li << 3);   // 8 channels (16B) per lane
    float2 a0 = {0.f,0.f}, a1 = {0.f,0.f}, a2 = {0.f,0.f}, a3 = {0.f,0.f};
#define PROC(r) { \
    uint4 uu = *(const uint4*)(sp + ((size_t)(unsigned)(r) << 7)); \
    float2 t0 = bfu(uu.x), t1 = bfu(uu.y), t2 = bfu(uu.z), t3 = bfu(uu.w); \
    a0.x += t0.x; a0.y += t0.y; a1.x += t1.x; a1.y += t1.y; \
    a2.x += t2.x; a2.y += t2.y; a3.x += t3.x; a3.y += t3.y; }
    int j = s0;
    for (; j + 16 <= s1; j += 16) {
        const int* ip = sidx + j + grp * 4;
        int r0 = ip[0], r1 = ip[1], r2 = ip[2], r3 = ip[3];
        PROC(r0); PROC(r1); PROC(r2); PROC(r3);
    }
    if (j < s1) {
        const int* ip = sidx + j + grp * 4;
        int base = j + grp * 4;
        if (base < s1)     PROC(ip[0]);
        if (base + 1 < s1) PROC(ip[1]);
        if (base + 2 < s1) PROC(ip[2]);
        if (base + 3 < s1) PROC(ip[3]);
    }
#undef PROC
#define RED(v) { v += __shfl_xor(v, 16); v += __shfl_xor(v, 32); }
    RED(a0.x) RED(a0.y) RED(a1.x) RED(a1.y)
    RED(a2.x) RED(a2.y) RED(a3.x) RED(a3.y)
#undef RED
    int c = s1 - s0;
    float inv = 1.f / (float)(c > 0 ? c : 1);
    a0.x *= inv; a0.y *= inv; a1.x *= inv; a1.y *= inv;
    a2.x *= inv; a2.y *= inv; a3.x *= inv; a3.y *= inv;
    if (grp != 0) return;
    int c0 = li << 3;
    if (MODE == 1) {
        a0.x = fmaxf(a0.x, 0.f); a0.y = fmaxf(a0.y, 0.f);
        a1.x = fmaxf(a1.x, 0.f); a1.y = fmaxf(a1.y, 0.f);
        a2.x = fmaxf(a2.x, 0.f); a2.y = fmaxf(a2.y, 0.f);
        a3.x = fmaxf(a3.x, 0.f); a3.y = fmaxf(a3.y, 0.f);
        float4 gA = *(const float4*)(g + c0),  gB = *(const float4*)(g + c0 + 4);
        float4 bA = *(const float4*)(b + c0),  bB = *(const float4*)(b + c0 + 4);
        float4 mA = *(const float4*)(mu + c0), mB = *(const float4*)(mu + c0 + 4);
        float4 vA = *(const float4*)(var + c0), vB = *(const float4*)(var + c0 + 4);
        a0.x = (a0.x - mA.x) * rsqrtf(vA.x + 1e-5f) * gA.x + bA.x;
        a0.y = (a0.y - mA.y) * rsqrtf(vA.y + 1e-5f) * gA.y + bA.y;
        a1.x = (a1.x - mA.z) * rsqrtf(vA.z + 1e-5f) * gA.z + bA.z;
        a1.y = (a1.y - mA.w) * rsqrtf(vA.w + 1e-5f) * gA.w + bA.w;
        a2.x = (a2.x - mB.x) * rsqrtf(vB.x + 1e-5f) * gB.x + bB.x;
        a2.y = (a2.y - mB.y) * rsqrtf(vB.y + 1e-5f) * gB.y + bB.y;
        a3.x = (a3.x - mB.z) * rsqrtf(vB.z + 1e-5f) * gB.z + bB.z;
        a3.y = (a3.y - mB.w) * rsqrtf(vB.w + 1e-5f) * gB.w + bB.w;
        uint4 u;
        u.x = (unsigned)f2bf(a0.x) | ((unsigned)f2bf(a0.y) << 16);
        u.y = (unsigned)f2bf(a1.x) | ((unsigned)f2bf(a1.y) << 16);
        u.z = (unsigned)f2bf(a2.x) | ((unsigned)f2bf(a2.y) << 16);
        u.w = (unsigned)f2bf(a3.x) | ((unsigned)f2bf(a3.y) << 16);
        *(uint4*)(out16 + (size_t)wave * 128 + c0) = u;
    } else {
        *(float4*)(outf + (size_t)wave * 128 + c0) = make_float4(a0.x, a0.y, a1.x, a1.y);
        *(float4*)(outf + (size_t)wave * 128 + c0 + 4) = make_float4(a2.x, a2.y, a3.x, a3.y);
    }
}

// ============ segment-mean, 40 bf16 ch + log_softmax, 16-lane groups ============
__global__ __launch_bounds__(256) void segred40ls(const unsigned short* __restrict__ src,
                                                  const int* __restrict__ sidx,
                                                  const int* __restrict__ off,
                                                  float* __restrict__ out, int nDest) {
    int wave = blockIdx.x * 4 + (threadIdx.x >> 6);
    if (wave >= nDest) return;
    int lane = threadIdx.x & 63;
    int grp = lane >> 4, li = lane & 15;
    int s0 = off[wave], s1 = off[wave + 1];
    const unsigned short* sp = src + (li << 2);   // 4 channels (8B) per lane; li>=10 reads pad
    float2 a0 = {0.f,0.f}, a1 = {0.f,0.f};
#define PROC(r) { \
    uint2 uu = *(const uint2*)(sp + (size_t)(unsigned)(r) * 40); \
    float2 t0 = bfu(uu.x), t1 = bfu(uu.y); \
    a0.x += t0.x; a0.y += t0.y; a1.x += t1.x; a1.y += t1.y; }
    int j = s0;
    for (; j + 16 <= s1; j += 16) {
        const int* ip = sidx + j + grp * 4;
        int r0 = ip[0], r1 = ip[1], r2 = ip[2], r3 = ip[3];
        PROC(r0); PROC(r1); PROC(r2); PROC(r3);
    }
    if (j < s1) {
        const int* ip = sidx + j + grp * 4;
        int base = j + grp * 4;
        if (base < s1)     PROC(ip[0]);
        if (base + 1 < s1) PROC(ip[1]);
        if (base + 2 < s1) PROC(ip[2]);
        if (base + 3 < s1) PROC(ip[3]);
    }
#undef PROC
#define RED(v) { v += __shfl_xor(v, 16); v += __shfl_xor(v, 32); }
    RED(a0.x) RED(a0.y) RED(a1.x) RED(a1.y)
#undef RED
    int c = s1 - s0;
    float inv = 1.f / (float)(c > 0 ? c : 1);
    a0.x *= inv; a0.y *= inv; a1.x *= inv; a1.y *= inv;
    bool act = li < 10;
    float mv = act ? fmaxf(fmaxf(a0.x, a0.y), fmaxf(a1.x, a1.y)) : -INFINITY;
#pragma unroll
    for (int o = 1; o < 16; o <<= 1) mv = fmaxf(mv, __shfl_xor(mv, o));
    float e = act ? (__expf(a0.x - mv) + __expf(a0.y - mv) + __expf(a1.x - mv) + __expf(a1.y - mv)) : 0.f;
#pragma unroll
    for (int o = 1; o < 16; o <<= 1) e += __shfl_xor(e, o);
    float ls = __logf(e);
    if (grp == 0 && act)
        *(float4*)(out + (size_t)wave * 40 + (li << 2)) =
            make_float4(a0.x - mv - ls, a0.y - mv - ls, a1.x - mv - ls, a1.y - mv - ls);
}

extern "C" void kernel_launch(void* const* d_in, const int* in_sizes, int n_in,
                              void* d_out, int out_size, void* d_ws, size_t ws_size,
                              hipStream_t stream) {
    const float* x    = (const float*)d_in[0];
    const int*   vids = (const int*)d_in[1];
    const int*   eids = (const int*)d_in[2];
    const float* w1a  = (const float*)d_in[3];
    const float* w1b  = (const float*)d_in[4];
    const float* w2a  = (const float*)d_in[5];
    const float* w2b  = (const float*)d_in[6];
    const float* g    = (const float*)d_in[7];
    const float* bta  = (const float*)d_in[8];
    const float* mu   = (const float*)d_in[9];
    const float* var  = (const float*)d_in[10];
    float* out = (float*)d_out;
    char*  ws  = (char*)d_ws;

    // ---- workspace layout (peak ~103 MB) ----
    int*            srcE = (int*)(ws);                        // 12.8 MB, live all call
    int*            srcV = (int*)(ws + 12800000);             // 12.8 MB, live all call
    unsigned*       pkE  = (unsigned*)(ws + 25600000);        // 12.8 MB, dead after s4
    unsigned*       pkV  = (unsigned*)(ws + 38400000);        // 12.8 MB, dead after s4
    unsigned short* hh   = (unsigned short*)(ws + 25600000);  // V*128 bf16 = 25.6 MB (overlays pk, dead)
    unsigned short* xh   = (unsigned short*)(ws + 51200000);  // V*128 bf16 = 25.6 MB, dead after 1st gather
    float*          mE   = (float*)(ws + 76800000);           // E*128 f32 = 10.24 MB (also mE2 later)
    float*          y    = (float*)(ws + 87040000);           // E*128 f32 = 10.24 MB
    unsigned short* y2h  = (unsigned short*)(ws + 97280000);  // E*128 bf16 = 5.12 MB
    float*          y3   = (float*)(ws + 87040000);           // E*40 f32 = 3.2 MB (overlays y, dead)
    unsigned short* y4h  = (unsigned short*)(ws + 90304000);  // E*40 bf16 = 1.6 MB (+pad slack in y region)
    int*            offE = (int*)(ws + 102400000);            // NE+1
    int*            offV = (int*)(ws + 102481024);            // NV+1
    int*            bbE  = (int*)(ws + 102882048);            // 257
    int*            bbV  = (int*)(ws + 102883328);            // 257
    int*            gcE  = (int*)(ws + 102884608);            // 256
    int*            gcV  = (int*)(ws + 102885888);            // 256
    int*            hb   = (int*)(ws + 102887168);            // 512

    // ---- CSR build + x->bf16 ----
    hipMemsetAsync(hb, 0, 512 * 4, stream);
    cvt_bf16<<<(NV * 32 + 255) / 256, 256, 0, stream>>>(x, xh, NV * 32);
    s1_hist<<<NBLK, 256, 0, stream>>>(vids, eids, hb);
    s2_scan<<<1, 64, 0, stream>>>(hb, bbE, bbV, gcE, gcV, offE, offV);
    s3_bin<<<NBLK, 256, 0, stream>>>(vids, eids, gcE, gcV, pkE, pkV);
    s4_sort<<<NBE + NBV, 256, 0, stream>>>(pkE, pkV, bbE, bbV, offE, offV, srcE, srcV);

    // ---- layer 1 (mean first; matmuls on E rows) ----
    segred128g<0><<<(NE + 3) / 4, 256, 0, stream>>>(xh, srcE, offE, mE, nullptr, NE,
                                                    nullptr, nullptr, nullptr, nullptr);
    mm_k128_n128<true, false><<<(NE + 31) / 32, 256, 0, stream>>>(mE, w1a, y, nullptr, NE);
    mm_k128_n128<false, true><<<(NE + 31) / 32, 256, 0, stream>>>(y, w1b, nullptr, y2h, NE);
    segred128g<1><<<(NV + 3) / 4, 256, 0, stream>>>(y2h, srcV, offV, nullptr, hh, NV,
                                                    g, bta, mu, var);

    // ---- layer 2 (second linearity swap: gather h, then small matmuls on E rows) ----
    segred128g<0><<<(NE + 3) / 4, 256, 0, stream>>>(hh, srcE, offE, mE, nullptr, NE,
                                                    nullptr, nullptr, nullptr, nullptr);
    mm_k128_n40<<<(NE + 23) / 24, 256, 0, stream>>>(mE, w2a, y3, NE);     // relu fused
    mm_k40_n40<<<(NE * 40 + 255) / 256, 256, 0, stream>>>(y3, w2b, y4h, NE);
    segred40ls<<<(NV + 3) / 4, 256, 0, stream>>>(y4h, srcV, offV, out, NV);
}

// Round 6
// 467.921 us; speedup vs baseline: 32.2948x; 1.2308x over previous
//
#include <hip/hip_runtime.h>
#include <hip/hip_bf16.h>

#define NV 100000
#define NE 20000
#define NNZ 3200000
#define CHUNK 4096
#define NBLK ((NNZ + CHUNK - 1) / CHUNK)   // 782
#define NBE 157   // E buckets: e>>7
#define NBV 196   // V buckets: v>>9

typedef float vf2 __attribute__((ext_vector_type(2)));

__device__ __forceinline__ unsigned short f2bf(float f) {
    unsigned u = __float_as_uint(f);
    u += 0x7fffu + ((u >> 16) & 1u);       // round-to-nearest-even
    return (unsigned short)(u >> 16);
}
__device__ __forceinline__ float2 bfu(unsigned u) {
    return make_float2(__uint_as_float(u << 16), __uint_as_float(u & 0xffff0000u));
}
// f32 -> e4m3fn with round-to-nearest-even (software: bias-free regardless of HW cvt mode)
__device__ __forceinline__ unsigned f2e4m3(float f) {
    unsigned u = __float_as_uint(f);
    unsigned s = (u >> 24) & 0x80u;
    unsigned a = u & 0x7FFFFFFFu;
    if (a >= 0x43E00000u) return s | 0x7Eu;            // clamp to 448
    if (a < 0x3C800000u) {                             // |f| < 2^-6: denormal
        int m = __float2int_rn(__uint_as_float(a) * 512.f);
        return s | (unsigned)m;
    }
    unsigned r = a + 0x7FFFFu + ((a >> 20) & 1u);      // RNE at 3 mantissa bits
    int e8 = (int)(r >> 23) - 120;
    if (e8 >= 16) return s | 0x7Eu;
    return s | ((unsigned)e8 << 3) | ((r >> 20) & 7u);
}

// ---------------- fp32 -> fp8 bulk convert (x) ----------------
__global__ __launch_bounds__(256) void cvt_fp8(const float* __restrict__ in,
                                               unsigned char* __restrict__ outp, int n8) {
    int i = blockIdx.x * 256 + threadIdx.x;
    if (i >= n8) return;
    float4 v0 = ((const float4*)in)[i * 2];
    float4 v1 = ((const float4*)in)[i * 2 + 1];
    unsigned lo = f2e4m3(v0.x) | (f2e4m3(v0.y) << 8) | (f2e4m3(v0.z) << 16) | (f2e4m3(v0.w) << 24);
    unsigned hi = f2e4m3(v1.x) | (f2e4m3(v1.y) << 8) | (f2e4m3(v1.z) << 16) | (f2e4m3(v1.w) << 24);
    ((uint2*)outp)[i] = make_uint2(lo, hi);
}

// ---------------- S1: coarse bucket histograms ----------------
__global__ __launch_bounds__(256) void s1_hist(const int* __restrict__ vids,
                                               const int* __restrict__ eids,
                                               int* __restrict__ hb) {
    __shared__ int h[512];
    for (int i = threadIdx.x; i < 512; i += 256) h[i] = 0;
    __syncthreads();
    int base = blockIdx.x * CHUNK;
#pragma unroll
    for (int k = 0; k < 16; ++k) {
        int i = base + k * 256 + threadIdx.x;
        if (i < NNZ) {
            atomicAdd(&h[eids[i] >> 7], 1);
            atomicAdd(&h[256 + (vids[i] >> 9)], 1);
        }
    }
    __syncthreads();
    for (int i = threadIdx.x; i < 512; i += 256)
        if (h[i]) atomicAdd(&hb[i], h[i]);
}

// ---------------- S2: scan bucket histograms ----------------
__global__ void s2_scan(const int* __restrict__ hb, int* __restrict__ bbE, int* __restrict__ bbV,
                        int* __restrict__ gcurE, int* __restrict__ gcurV,
                        int* __restrict__ offE, int* __restrict__ offV) {
    int t = threadIdx.x;
    if (t == 0) {
        int run = 0;
        for (int b = 0; b < 256; ++b) { bbE[b] = run; gcurE[b] = run; run += hb[b]; }
        bbE[256] = run; offE[NE] = run;
    } else if (t == 1) {
        int run = 0;
        for (int b = 0; b < 256; ++b) { bbV[b] = run; gcurV[b] = run; run += hb[256 + b]; }
        bbV[256] = run; offV[NV] = run;
    }
}

// ---------------- S3: binned scatter ----------------
__global__ __launch_bounds__(256) void s3_bin(const int* __restrict__ vids,
                                              const int* __restrict__ eids,
                                              int* __restrict__ gcurE, int* __restrict__ gcurV,
                                              unsigned* __restrict__ pkE, unsigned* __restrict__ pkV) {
    __shared__ int h[256], sc[256], gp[256];
    __shared__ unsigned staged[CHUNK];
    __shared__ unsigned char sb[CHUNK];
    int tid = threadIdx.x;
    int base = blockIdx.x * CHUNK;
    int n = NNZ - base; if (n > CHUNK) n = CHUNK;
    unsigned pe[16], pv[16];
#pragma unroll
    for (int k = 0; k < 16; ++k) {
        int i = base + k * 256 + tid;
        pe[k] = 0u; pv[k] = 0u;
        if (i < NNZ) {
            unsigned e = (unsigned)eids[i], v = (unsigned)vids[i];
            pe[k] = (e << 17) | v;
            pv[k] = (v << 15) | e;
        }
    }
    // E side
    h[tid] = 0;
    __syncthreads();
#pragma unroll
    for (int k = 0; k < 16; ++k)
        if (base + k * 256 + tid < NNZ) atomicAdd(&h[pe[k] >> 24], 1);
    __syncthreads();
    if (tid == 0) { int run = 0; for (int b = 0; b < 256; ++b) { int c = h[b]; h[b] = run; sc[b] = run; run += c; } }
    __syncthreads();
#pragma unroll
    for (int k = 0; k < 16; ++k)
        if (base + k * 256 + tid < NNZ) {
            int b = pe[k] >> 24;
            int pos = atomicAdd(&h[b], 1);
            staged[pos] = pe[k]; sb[pos] = (unsigned char)b;
        }
    __syncthreads();
    { int cnt = h[tid] - sc[tid]; gp[tid] = cnt ? atomicAdd(&gcurE[tid], cnt) : 0; }
    __syncthreads();
    for (int i = tid; i < n; i += 256) {
        int b = sb[i];
        pkE[gp[b] + (i - sc[b])] = staged[i];
    }
    __syncthreads();
    // V side
    h[tid] = 0;
    __syncthreads();
#pragma unroll
    for (int k = 0; k < 16; ++k)
        if (base + k * 256 + tid < NNZ) atomicAdd(&h[pv[k] >> 24], 1);
    __syncthreads();
    if (tid == 0) { int run = 0; for (int b = 0; b < 256; ++b) { int c = h[b]; h[b] = run; sc[b] = run; run += c; } }
    __syncthreads();
#pragma unroll
    for (int k = 0; k < 16; ++k)
        if (base + k * 256 + tid < NNZ) {
            int b = pv[k] >> 24;
            int pos = atomicAdd(&h[b], 1);
            staged[pos] = pv[k]; sb[pos] = (unsigned char)b;
        }
    __syncthreads();
    { int cnt = h[tid] - sc[tid]; gp[tid] = cnt ? atomicAdd(&gcurV[tid], cnt) : 0; }
    __syncthreads();
    for (int i = tid; i < n; i += 256) {
        int b = sb[i];
        pkV[gp[b] + (i - sc[b])] = staged[i];
    }
}

// ---------------- S4: per-bucket fine counting sort ----------------
__global__ __launch_bounds__(256) void s4_sort(const unsigned* __restrict__ pkE,
                                               const unsigned* __restrict__ pkV,
                                               const int* __restrict__ bbE, const int* __restrict__ bbV,
                                               int* __restrict__ offE, int* __restrict__ offV,
                                               int* __restrict__ srcE, int* __restrict__ srcV) {
    __shared__ int h[512];
    int blk = blockIdx.x, tid = threadIdx.x;
    bool isE = blk < NBE;
    const unsigned* pk = isE ? pkE : pkV;
    const int* bb = isE ? bbE : bbV;
    int* off = isE ? offE : offV;
    int* srcO = isE ? srcE : srcV;
    int b = isE ? blk : blk - NBE;
    int NLOC = isE ? 128 : 512;
    int SH = isE ? 17 : 15;
    int LM = NLOC - 1;
    unsigned PM = isE ? 0x1FFFFu : 0x7FFFu;
    int d0 = isE ? (b << 7) : (b << 9);
    int nD = isE ? NE : NV;
    int base = bb[b], end = bb[b + 1];
    for (int l = tid; l < NLOC; l += 256) h[l] = 0;
    __syncthreads();
    for (int i = base + tid; i < end; i += 256)
        atomicAdd(&h[(pk[i] >> SH) & LM], 1);
    __syncthreads();
    if (tid == 0) { int run = 0; for (int l = 0; l < NLOC; ++l) { int c = h[l]; h[l] = run; run += c; } }
    __syncthreads();
    for (int l = tid; l < NLOC; l += 256) { int d = d0 + l; if (d < nD) off[d] = base + h[l]; }
    __syncthreads();
    for (int i = base + tid; i < end; i += 256) {
        unsigned p = pk[i];
        int pos = atomicAdd(&h[(p >> SH) & LM], 1);
        srcO[base + pos] = (int)(p & PM);
    }
}

// ---------------- A[M x 128] @ W[128 x 128]; OUT: 0=f32 (opt relu), 2=fp8 ----------------
template <bool RELU, int OUT>
__global__ __launch_bounds__(256) void mm_k128_n128(const float* __restrict__ A,
                                                    const float* __restrict__ W,
                                                    float* __restrict__ out,
                                                    unsigned char* __restrict__ out8, int M) {
    __shared__ float Wl[128 * 128];
    __shared__ float Al[32 * 128];
    for (int i = threadIdx.x; i < 4096; i += 256)
        ((float4*)Wl)[i] = ((const float4*)W)[i];
    int row0 = blockIdx.x * 32;
    for (int i = threadIdx.x; i < 1024; i += 256) {
        int r = i >> 5, c4 = i & 31;
        int row = row0 + r;
        float4 v = make_float4(0.f, 0.f, 0.f, 0.f);
        if (row < M) v = ((const float4*)(A + (size_t)row * 128))[c4];
        ((float4*)Al)[i] = v;
    }
    __syncthreads();
    int cx = (threadIdx.x & 31) * 4;
    int rg = (threadIdx.x >> 5) * 4;
    float acc[4][4] = {};
#pragma unroll 8
    for (int k = 0; k < 128; ++k) {
        float4 w = *(const float4*)&Wl[k * 128 + cx];
#pragma unroll
        for (int r = 0; r < 4; ++r) {
            float a = Al[(rg + r) * 128 + k];
            acc[r][0] = fmaf(a, w.x, acc[r][0]);
            acc[r][1] = fmaf(a, w.y, acc[r][1]);
            acc[r][2] = fmaf(a, w.z, acc[r][2]);
            acc[r][3] = fmaf(a, w.w, acc[r][3]);
        }
    }
#pragma unroll
    for (int r = 0; r < 4; ++r) {
        int row = row0 + rg + r;
        if (row < M) {
            float4 o = make_float4(acc[r][0], acc[r][1], acc[r][2], acc[r][3]);
            if (RELU) {
                o.x = fmaxf(o.x, 0.f); o.y = fmaxf(o.y, 0.f);
                o.z = fmaxf(o.z, 0.f); o.w = fmaxf(o.w, 0.f);
            }
            if (OUT == 2) {
                unsigned pw = f2e4m3(o.x) | (f2e4m3(o.y) << 8) | (f2e4m3(o.z) << 16) | (f2e4m3(o.w) << 24);
                *(unsigned*)&out8[(size_t)row * 128 + cx] = pw;
            } else {
                *(float4*)&out[(size_t)row * 128 + cx] = o;
            }
        }
    }
}

// ---------------- A[M x 128] @ W[128 x 40] -> relu -> f32 out ----------------
__global__ __launch_bounds__(256) void mm_k128_n40(const float* __restrict__ A,
                                                   const float* __restrict__ W,
                                                   float* __restrict__ out, int M) {
    __shared__ float Wl[128 * 40];
    __shared__ float Al[24 * 128];
    for (int i = threadIdx.x; i < 1280; i += 256)
        ((float4*)Wl)[i] = ((const float4*)W)[i];
    int row0 = blockIdx.x * 24;
    for (int i = threadIdx.x; i < 768; i += 256) {
        int r = i >> 5, c4 = i & 31;
        int row = row0 + r;
        float4 v = make_float4(0.f, 0.f, 0.f, 0.f);
        if (row < M) v = ((const float4*)(A + (size_t)row * 128))[c4];
        ((float4*)Al)[i] = v;
    }
    __syncthreads();
    if (threadIdx.x >= 240) return;
    int col = threadIdx.x % 40;
    int rg = (threadIdx.x / 40) * 4;
    float acc[4] = {};
#pragma unroll 8
    for (int k = 0; k < 128; ++k) {
        float w = Wl[k * 40 + col];
#pragma unroll
        for (int r = 0; r < 4; ++r)
            acc[r] = fmaf(Al[(rg + r) * 128 + k], w, acc[r]);
    }
#pragma unroll
    for (int r = 0; r < 4; ++r) {
        int row = row0 + rg + r;
        if (row < M) out[(size_t)row * 40 + col] = fmaxf(acc[r], 0.f);
    }
}

// ---------------- A[M x 40] @ W[40 x 40] -> bf16 out ----------------
__global__ __launch_bounds__(256) void mm_k40_n40(const float* __restrict__ A,
                                                  const float* __restrict__ W,
                                                  unsigned short* __restrict__ out16, int M) {
    __shared__ float Wl[1600];
    for (int i = threadIdx.x; i < 400; i += 256)
        ((float4*)Wl)[i] = ((const float4*)W)[i];
    __syncthreads();
    int idx = blockIdx.x * 256 + threadIdx.x;
    int row = idx / 40, col = idx % 40;
    if (row >= M) return;
    const float* a = A + (size_t)row * 40;
    float acc = 0.f;
#pragma unroll
    for (int k = 0; k < 40; ++k)
        acc = fmaf(a[k], Wl[k * 40 + col], acc);
    out16[idx] = f2bf(acc);
}

// ============ segment-mean, 128 fp8 ch, 16-lane groups (4 rows / load) ============
// MODE 0: plain -> f32 out. MODE 1: relu+bn -> fp8 out.
template <int MODE>
__global__ __launch_bounds__(256) void segred128g8(const unsigned char* __restrict__ src,
                                                   const int* __restrict__ sidx,
                                                   const int* __restrict__ off,
                                                   float* __restrict__ outf,
                                                   unsigned char* __restrict__ out8,
                                                   int nDest,
                                                   const float* __restrict__ g,
                                                   const float* __restrict__ b,
                                                   const float* __restrict__ mu,
                                                   const float* __restrict__ var) {
    int wave = blockIdx.x * 4 + (threadIdx.x >> 6);
    if (wave >= nDest) return;
    int lane = threadIdx.x & 63;
    int grp = lane >> 4, li = lane & 15;
    int s0 = off[wave], s1 = off[wave + 1];
    const unsigned char* sp = src + (li << 3);   // 8 channels (8B) per lane
    vf2 a0 = {0.f, 0.f}, a1 = {0.f, 0.f}, a2 = {0.f, 0.f}, a3 = {0.f, 0.f};
#define PROC(r) { \
    uint2 uu = *(const uint2*)(sp + ((size_t)(unsigned)(r) << 7)); \
    a0 += __builtin_amdgcn_cvt_pk_f32_fp8((int)uu.x, false); \
    a1 += __builtin_amdgcn_cvt_pk_f32_fp8((int)uu.x, true); \
    a2 += __builtin_amdgcn_cvt_pk_f32_fp8((int)uu.y, false); \
    a3 += __builtin_amdgcn_cvt_pk_f32_fp8((int)uu.y, true); }
    int j = s0;
    for (; j + 16 <= s1; j += 16) {
        const int* ip = sidx + j + grp * 4;
        int r0 = ip[0], r1 = ip[1], r2 = ip[2], r3 = ip[3];
        PROC(r0); PROC(r1); PROC(r2); PROC(r3);
    }
    if (j < s1) {
        const int* ip = sidx + j + grp * 4;
        int base = j + grp * 4;
        if (base < s1)     PROC(ip[0]);
        if (base + 1 < s1) PROC(ip[1]);
        if (base + 2 < s1) PROC(ip[2]);
        if (base + 3 < s1) PROC(ip[3]);
    }
#undef PROC
#define RED(v) { v += __shfl_xor(v, 16); v += __shfl_xor(v, 32); }
    RED(a0.x) RED(a0.y) RED(a1.x) RED(a1.y)
    RED(a2.x) RED(a2.y) RED(a3.x) RED(a3.y)
#undef RED
    int c = s1 - s0;
    float inv = 1.f / (float)(c > 0 ? c : 1);
    a0 *= inv; a1 *= inv; a2 *= inv; a3 *= inv;
    if (grp != 0) return;
    int c0 = li << 3;
    if (MODE == 1) {
        a0.x = fmaxf(a0.x, 0.f); a0.y = fmaxf(a0.y, 0.f);
        a1.x = fmaxf(a1.x, 0.f); a1.y = fmaxf(a1.y, 0.f);
        a2.x = fmaxf(a2.x, 0.f); a2.y = fmaxf(a2.y, 0.f);
        a3.x = fmaxf(a3.x, 0.f); a3.y = fmaxf(a3.y, 0.f);
        float4 gA = *(const float4*)(g + c0),  gB = *(const float4*)(g + c0 + 4);
        float4 bA = *(const float4*)(b + c0),  bB = *(const float4*)(b + c0 + 4);
        float4 mA = *(const float4*)(mu + c0), mB = *(const float4*)(mu + c0 + 4);
        float4 vA = *(const float4*)(var + c0), vB = *(const float4*)(var + c0 + 4);
        a0.x = (a0.x - mA.x) * rsqrtf(vA.x + 1e-5f) * gA.x + bA.x;
        a0.y = (a0.y - mA.y) * rsqrtf(vA.y + 1e-5f) * gA.y + bA.y;
        a1.x = (a1.x - mA.z) * rsqrtf(vA.z + 1e-5f) * gA.z + bA.z;
        a1.y = (a1.y - mA.w) * rsqrtf(vA.w + 1e-5f) * gA.w + bA.w;
        a2.x = (a2.x - mB.x) * rsqrtf(vB.x + 1e-5f) * gB.x + bB.x;
        a2.y = (a2.y - mB.y) * rsqrtf(vB.y + 1e-5f) * gB.y + bB.y;
        a3.x = (a3.x - mB.z) * rsqrtf(vB.z + 1e-5f) * gB.z + bB.z;
        a3.y = (a3.y - mB.w) * rsqrtf(vB.w + 1e-5f) * gB.w + bB.w;
        unsigned lo = f2e4m3(a0.x) | (f2e4m3(a0.y) << 8) | (f2e4m3(a1.x) << 16) | (f2e4m3(a1.y) << 24);
        unsigned hi = f2e4m3(a2.x) | (f2e4m3(a2.y) << 8) | (f2e4m3(a3.x) << 16) | (f2e4m3(a3.y) << 24);
        *(uint2*)(out8 + (size_t)wave * 128 + c0) = make_uint2(lo, hi);
    } else {
        *(float4*)(outf + (size_t)wave * 128 + c0) = make_float4(a0.x, a0.y, a1.x, a1.y);
        *(float4*)(outf + (size_t)wave * 128 + c0 + 4) = make_float4(a2.x, a2.y, a3.x, a3.y);
    }
}

// ============ segment-mean, 40 bf16 ch + log_softmax, 16-lane groups ============
__global__ __launch_bounds__(256) void segred40ls(const unsigned short* __restrict__ src,
                                                  const int* __restrict__ sidx,
                                                  const int* __restrict__ off,
                                                  float* __restrict__ out, int nDest) {
    int wave = blockIdx.x * 4 + (threadIdx.x >> 6);
    if (wave >= nDest) return;
    int lane = threadIdx.x & 63;
    int grp = lane >> 4, li = lane & 15;
    int s0 = off[wave], s1 = off[wave + 1];
    const unsigned short* sp = src + (li << 2);   // 4 channels (8B) per lane; li>=10 reads pad
    float2 a0 = {0.f,0.f}, a1 = {0.f,0.f};
#define PROC(r) { \
    uint2 uu = *(const uint2*)(sp + (size_t)(unsigned)(r) * 40); \
    float2 t0 = bfu(uu.x), t1 = bfu(uu.y); \
    a0.x += t0.x; a0.y += t0.y; a1.x += t1.x; a1.y += t1.y; }
    int j = s0;
    for (; j + 16 <= s1; j += 16) {
        const int* ip = sidx + j + grp * 4;
        int r0 = ip[0], r1 = ip[1], r2 = ip[2], r3 = ip[3];
        PROC(r0); PROC(r1); PROC(r2); PROC(r3);
    }
    if (j < s1) {
        const int* ip = sidx + j + grp * 4;
        int base = j + grp * 4;
        if (base < s1)     PROC(ip[0]);
        if (base + 1 < s1) PROC(ip[1]);
        if (base + 2 < s1) PROC(ip[2]);
        if (base + 3 < s1) PROC(ip[3]);
    }
#undef PROC
#define RED(v) { v += __shfl_xor(v, 16); v += __shfl_xor(v, 32); }
    RED(a0.x) RED(a0.y) RED(a1.x) RED(a1.y)
#undef RED
    int c = s1 - s0;
    float inv = 1.f / (float)(c > 0 ? c : 1);
    a0.x *= inv; a0.y *= inv; a1.x *= inv; a1.y *= inv;
    bool act = li < 10;
    float mv = act ? fmaxf(fmaxf(a0.x, a0.y), fmaxf(a1.x, a1.y)) : -INFINITY;
#pragma unroll
    for (int o = 1; o < 16; o <<= 1) mv = fmaxf(mv, __shfl_xor(mv, o));
    float e = act ? (__expf(a0.x - mv) + __expf(a0.y - mv) + __expf(a1.x - mv) + __expf(a1.y - mv)) : 0.f;
#pragma unroll
    for (int o = 1; o < 16; o <<= 1) e += __shfl_xor(e, o);
    float ls = __logf(e);
    if (grp == 0 && act)
        *(float4*)(out + (size_t)wave * 40 + (li << 2)) =
            make_float4(a0.x - mv - ls, a0.y - mv - ls, a1.x - mv - ls, a1.y - mv - ls);
}

extern "C" void kernel_launch(void* const* d_in, const int* in_sizes, int n_in,
                              void* d_out, int out_size, void* d_ws, size_t ws_size,
                              hipStream_t stream) {
    const float* x    = (const float*)d_in[0];
    const int*   vids = (const int*)d_in[1];
    const int*   eids = (const int*)d_in[2];
    const float* w1a  = (const float*)d_in[3];
    const float* w1b  = (const float*)d_in[4];
    const float* w2a  = (const float*)d_in[5];
    const float* w2b  = (const float*)d_in[6];
    const float* g    = (const float*)d_in[7];
    const float* bta  = (const float*)d_in[8];
    const float* mu   = (const float*)d_in[9];
    const float* var  = (const float*)d_in[10];
    float* out = (float*)d_out;
    char*  ws  = (char*)d_ws;

    // ---- workspace layout (peak ~105.2 MB; 110.5 MB was accepted in R1) ----
    int*            srcE = (int*)(ws);                        //  0      .. 12.8M
    int*            srcV = (int*)(ws + 12800000);             // 12.8M   .. 25.6M
    unsigned*       pkE  = (unsigned*)(ws + 25600000);        // 25.6M   .. 38.4M (dead after s4)
    unsigned*       pkV  = (unsigned*)(ws + 38400000);        // 38.4M   .. 51.2M (dead after s4)
    unsigned char*  xh8  = (unsigned char*)(ws + 51200000);   // V*128 fp8 = 12.8 MB
    unsigned char*  hh8  = (unsigned char*)(ws + 64000000);   // V*128 fp8 = 12.8 MB
    float*          mE   = (float*)(ws + 76800000);           // E*128 f32 = 10.24 MB
    float*          y    = (float*)(ws + 87040000);           // E*128 f32 = 10.24 MB
    unsigned char*  y28  = (unsigned char*)(ws + 97280000);   // E*128 fp8 = 2.56 MB (L2-resident!)
    float*          y3   = (float*)(ws + 99840000);           // E*40 f32 = 3.2 MB
    unsigned short* y4h  = (unsigned short*)(ws + 103040000); // E*40 bf16 = 1.6 MB
    int*            offE = (int*)(ws + 104640000);            // NE+1
    int*            offV = (int*)(ws + 104720128);            // NV+1
    int*            bbE  = (int*)(ws + 105120256);            // 257
    int*            bbV  = (int*)(ws + 105122304);            // 257
    int*            gcE  = (int*)(ws + 105124352);            // 256
    int*            gcV  = (int*)(ws + 105126400);            // 256
    int*            hb   = (int*)(ws + 105128448);            // 512

    // ---- CSR build + x->fp8 ----
    hipMemsetAsync(hb, 0, 512 * 4, stream);
    cvt_fp8<<<(NV * 16 + 255) / 256, 256, 0, stream>>>(x, xh8, NV * 16);
    s1_hist<<<NBLK, 256, 0, stream>>>(vids, eids, hb);
    s2_scan<<<1, 64, 0, stream>>>(hb, bbE, bbV, gcE, gcV, offE, offV);
    s3_bin<<<NBLK, 256, 0, stream>>>(vids, eids, gcE, gcV, pkE, pkV);
    s4_sort<<<NBE + NBV, 256, 0, stream>>>(pkE, pkV, bbE, bbV, offE, offV, srcE, srcV);

    // ---- layer 1 (mean first; matmuls on E rows) ----
    segred128g8<0><<<(NE + 3) / 4, 256, 0, stream>>>(xh8, srcE, offE, mE, nullptr, NE,
                                                     nullptr, nullptr, nullptr, nullptr);
    mm_k128_n128<true, 0><<<(NE + 31) / 32, 256, 0, stream>>>(mE, w1a, y, nullptr, NE);
    mm_k128_n128<false, 2><<<(NE + 31) / 32, 256, 0, stream>>>(y, w1b, nullptr, y28, NE);
    segred128g8<1><<<(NV + 3) / 4, 256, 0, stream>>>(y28, srcV, offV, nullptr, hh8, NV,
                                                     g, bta, mu, var);

    // ---- layer 2 (second linearity swap) ----
    segred128g8<0><<<(NE + 3) / 4, 256, 0, stream>>>(hh8, srcE, offE, mE, nullptr, NE,
                                                     nullptr, nullptr, nullptr, nullptr);
    mm_k128_n40<<<(NE + 23) / 24, 256, 0, stream>>>(mE, w2a, y3, NE);     // relu fused
    mm_k40_n40<<<(NE * 40 + 255) / 256, 256, 0, stream>>>(y3, w2b, y4h, NE);
    segred40ls<<<(NV + 3) / 4, 256, 0, stream>>>(y4h, srcV, offV, out, NV);
}

// Round 8
// 447.952 us; speedup vs baseline: 33.7345x; 1.0446x over previous
//
#include <hip/hip_runtime.h>
#include <hip/hip_bf16.h>

#define NV 100000
#define NE 20000
#define NNZ 3200000
#define CHUNK 4096
#define NBLK ((NNZ + CHUNK - 1) / CHUNK)   // 782
#define NBE 157   // E buckets: e>>7
#define NBV 196   // V buckets: v>>9

typedef float vf2 __attribute__((ext_vector_type(2)));

__device__ __forceinline__ unsigned short f2bf(float f) {
    unsigned u = __float_as_uint(f);
    u += 0x7fffu + ((u >> 16) & 1u);       // round-to-nearest-even
    return (unsigned short)(u >> 16);
}
__device__ __forceinline__ float2 bfu(unsigned u) {
    return make_float2(__uint_as_float(u << 16), __uint_as_float(u & 0xffff0000u));
}
// HW packed f32->fp8(e4m3) encode. Word-select must be a compile-time constant.
template <bool HI>
__device__ __forceinline__ int pk8(float a, float b, int old) {
    return __builtin_amdgcn_cvt_pk_fp8_f32(a, b, old, HI);
}

// ---------------- fp32 -> fp8 bulk convert (x) ----------------
__global__ __launch_bounds__(256) void cvt_fp8(const float* __restrict__ in,
                                               unsigned char* __restrict__ outp, int n8) {
    int i = blockIdx.x * 256 + threadIdx.x;
    if (i >= n8) return;
    float4 v0 = ((const float4*)in)[i * 2];
    float4 v1 = ((const float4*)in)[i * 2 + 1];
    int lo = pk8<false>(v0.x, v0.y, 0); lo = pk8<true>(v0.z, v0.w, lo);
    int hi = pk8<false>(v1.x, v1.y, 0); hi = pk8<true>(v1.z, v1.w, hi);
    ((int2*)outp)[i] = make_int2(lo, hi);
}

// ---------------- S1: coarse bucket histograms ----------------
__global__ __launch_bounds__(256) void s1_hist(const int* __restrict__ vids,
                                               const int* __restrict__ eids,
                                               int* __restrict__ hb) {
    __shared__ int h[512];
    for (int i = threadIdx.x; i < 512; i += 256) h[i] = 0;
    __syncthreads();
    int base = blockIdx.x * CHUNK;
#pragma unroll
    for (int k = 0; k < 16; ++k) {
        int i = base + k * 256 + threadIdx.x;
        if (i < NNZ) {
            atomicAdd(&h[eids[i] >> 7], 1);
            atomicAdd(&h[256 + (vids[i] >> 9)], 1);
        }
    }
    __syncthreads();
    for (int i = threadIdx.x; i < 512; i += 256)
        if (h[i]) atomicAdd(&hb[i], h[i]);
}

// ---------------- S2: scan bucket histograms + BN fold ----------------
__global__ void s2_scan(const int* __restrict__ hb, int* __restrict__ bbE, int* __restrict__ bbV,
                        int* __restrict__ gcurE, int* __restrict__ gcurV,
                        int* __restrict__ offE, int* __restrict__ offV,
                        const float* __restrict__ g, const float* __restrict__ b,
                        const float* __restrict__ mu, const float* __restrict__ var,
                        float* __restrict__ bnsc, float* __restrict__ bnsh) {
    int t = threadIdx.x;
    if (t < 128) {
        float sc = g[t] * rsqrtf(var[t] + 1e-5f);
        bnsc[t] = sc;
        bnsh[t] = b[t] - mu[t] * sc;
    }
    if (t == 0) {
        int run = 0;
        for (int bb = 0; bb < 256; ++bb) { bbE[bb] = run; gcurE[bb] = run; run += hb[bb]; }
        bbE[256] = run; offE[NE] = run;
    } else if (t == 1) {
        int run = 0;
        for (int bb = 0; bb < 256; ++bb) { bbV[bb] = run; gcurV[bb] = run; run += hb[256 + bb]; }
        bbV[256] = run; offV[NV] = run;
    }
}

// ---------------- S3: binned scatter ----------------
__global__ __launch_bounds__(256) void s3_bin(const int* __restrict__ vids,
                                              const int* __restrict__ eids,
                                              int* __restrict__ gcurE, int* __restrict__ gcurV,
                                              unsigned* __restrict__ pkE, unsigned* __restrict__ pkV) {
    __shared__ int h[256], sc[256], gp[256];
    __shared__ unsigned staged[CHUNK];
    __shared__ unsigned char sb[CHUNK];
    int tid = threadIdx.x;
    int base = blockIdx.x * CHUNK;
    int n = NNZ - base; if (n > CHUNK) n = CHUNK;
    unsigned pe[16], pv[16];
#pragma unroll
    for (int k = 0; k < 16; ++k) {
        int i = base + k * 256 + tid;
        pe[k] = 0u; pv[k] = 0u;
        if (i < NNZ) {
            unsigned e = (unsigned)eids[i], v = (unsigned)vids[i];
            pe[k] = (e << 17) | v;
            pv[k] = (v << 15) | e;
        }
    }
    // E side
    h[tid] = 0;
    __syncthreads();
#pragma unroll
    for (int k = 0; k < 16; ++k)
        if (base + k * 256 + tid < NNZ) atomicAdd(&h[pe[k] >> 24], 1);
    __syncthreads();
    if (tid == 0) { int run = 0; for (int b = 0; b < 256; ++b) { int c = h[b]; h[b] = run; sc[b] = run; run += c; } }
    __syncthreads();
#pragma unroll
    for (int k = 0; k < 16; ++k)
        if (base + k * 256 + tid < NNZ) {
            int b = pe[k] >> 24;
            int pos = atomicAdd(&h[b], 1);
            staged[pos] = pe[k]; sb[pos] = (unsigned char)b;
        }
    __syncthreads();
    { int cnt = h[tid] - sc[tid]; gp[tid] = cnt ? atomicAdd(&gcurE[tid], cnt) : 0; }
    __syncthreads();
    for (int i = tid; i < n; i += 256) {
        int b = sb[i];
        pkE[gp[b] + (i - sc[b])] = staged[i];
    }
    __syncthreads();
    // V side
    h[tid] = 0;
    __syncthreads();
#pragma unroll
    for (int k = 0; k < 16; ++k)
        if (base + k * 256 + tid < NNZ) atomicAdd(&h[pv[k] >> 24], 1);
    __syncthreads();
    if (tid == 0) { int run = 0; for (int b = 0; b < 256; ++b) { int c = h[b]; h[b] = run; sc[b] = run; run += c; } }
    __syncthreads();
#pragma unroll
    for (int k = 0; k < 16; ++k)
        if (base + k * 256 + tid < NNZ) {
            int b = pv[k] >> 24;
            int pos = atomicAdd(&h[b], 1);
            staged[pos] = pv[k]; sb[pos] = (unsigned char)b;
        }
    __syncthreads();
    { int cnt = h[tid] - sc[tid]; gp[tid] = cnt ? atomicAdd(&gcurV[tid], cnt) : 0; }
    __syncthreads();
    for (int i = tid; i < n; i += 256) {
        int b = sb[i];
        pkV[gp[b] + (i - sc[b])] = staged[i];
    }
}

// ---------------- S4: per-bucket fine counting sort ----------------
__global__ __launch_bounds__(256) void s4_sort(const unsigned* __restrict__ pkE,
                                               const unsigned* __restrict__ pkV,
                                               const int* __restrict__ bbE, const int* __restrict__ bbV,
                                               int* __restrict__ offE, int* __restrict__ offV,
                                               int* __restrict__ srcE, int* __restrict__ srcV) {
    __shared__ int h[512];
    int blk = blockIdx.x, tid = threadIdx.x;
    bool isE = blk < NBE;
    const unsigned* pk = isE ? pkE : pkV;
    const int* bb = isE ? bbE : bbV;
    int* off = isE ? offE : offV;
    int* srcO = isE ? srcE : srcV;
    int b = isE ? blk : blk - NBE;
    int NLOC = isE ? 128 : 512;
    int SH = isE ? 17 : 15;
    int LM = NLOC - 1;
    unsigned PM = isE ? 0x1FFFFu : 0x7FFFu;
    int d0 = isE ? (b << 7) : (b << 9);
    int nD = isE ? NE : NV;
    int base = bb[b], end = bb[b + 1];
    for (int l = tid; l < NLOC; l += 256) h[l] = 0;
    __syncthreads();
    for (int i = base + tid; i < end; i += 256)
        atomicAdd(&h[(pk[i] >> SH) & LM], 1);
    __syncthreads();
    if (tid == 0) { int run = 0; for (int l = 0; l < NLOC; ++l) { int c = h[l]; h[l] = run; run += c; } }
    __syncthreads();
    for (int l = tid; l < NLOC; l += 256) { int d = d0 + l; if (d < nD) off[d] = base + h[l]; }
    __syncthreads();
    for (int i = base + tid; i < end; i += 256) {
        unsigned p = pk[i];
        int pos = atomicAdd(&h[(p >> SH) & LM], 1);
        srcO[base + pos] = (int)(p & PM);
    }
}

// ---------------- A[M x 128] @ W[128 x 128]; OUT: 0=f32 (opt relu), 2=fp8 ----------------
template <bool RELU, int OUT>
__global__ __launch_bounds__(256) void mm_k128_n128(const float* __restrict__ A,
                                                    const float* __restrict__ W,
                                                    float* __restrict__ out,
                                                    unsigned char* __restrict__ out8, int M) {
    __shared__ float Wl[128 * 128];
    __shared__ float Al[32 * 128];
    for (int i = threadIdx.x; i < 4096; i += 256)
        ((float4*)Wl)[i] = ((const float4*)W)[i];
    int row0 = blockIdx.x * 32;
    for (int i = threadIdx.x; i < 1024; i += 256) {
        int r = i >> 5, c4 = i & 31;
        int row = row0 + r;
        float4 v = make_float4(0.f, 0.f, 0.f, 0.f);
        if (row < M) v = ((const float4*)(A + (size_t)row * 128))[c4];
        ((float4*)Al)[i] = v;
    }
    __syncthreads();
    int cx = (threadIdx.x & 31) * 4;
    int rg = (threadIdx.x >> 5) * 4;
    float acc[4][4] = {};
#pragma unroll 8
    for (int k = 0; k < 128; ++k) {
        float4 w = *(const float4*)&Wl[k * 128 + cx];
#pragma unroll
        for (int r = 0; r < 4; ++r) {
            float a = Al[(rg + r) * 128 + k];
            acc[r][0] = fmaf(a, w.x, acc[r][0]);
            acc[r][1] = fmaf(a, w.y, acc[r][1]);
            acc[r][2] = fmaf(a, w.z, acc[r][2]);
            acc[r][3] = fmaf(a, w.w, acc[r][3]);
        }
    }
#pragma unroll
    for (int r = 0; r < 4; ++r) {
        int row = row0 + rg + r;
        if (row < M) {
            float4 o = make_float4(acc[r][0], acc[r][1], acc[r][2], acc[r][3]);
            if (RELU) {
                o.x = fmaxf(o.x, 0.f); o.y = fmaxf(o.y, 0.f);
                o.z = fmaxf(o.z, 0.f); o.w = fmaxf(o.w, 0.f);
            }
            if (OUT == 2) {
                int pw = pk8<false>(o.x, o.y, 0);
                pw = pk8<true>(o.z, o.w, pw);
                *(int*)&out8[(size_t)row * 128 + cx] = pw;
            } else {
                *(float4*)&out[(size_t)row * 128 + cx] = o;
            }
        }
    }
}

// ---------------- A[M x 128] @ W[128 x 40] -> relu -> f32 out ----------------
__global__ __launch_bounds__(256) void mm_k128_n40(const float* __restrict__ A,
                                                   const float* __restrict__ W,
                                                   float* __restrict__ out, int M) {
    __shared__ float Wl[128 * 40];
    __shared__ float Al[24 * 128];
    for (int i = threadIdx.x; i < 1280; i += 256)
        ((float4*)Wl)[i] = ((const float4*)W)[i];
    int row0 = blockIdx.x * 24;
    for (int i = threadIdx.x; i < 768; i += 256) {
        int r = i >> 5, c4 = i & 31;
        int row = row0 + r;
        float4 v = make_float4(0.f, 0.f, 0.f, 0.f);
        if (row < M) v = ((const float4*)(A + (size_t)row * 128))[c4];
        ((float4*)Al)[i] = v;
    }
    __syncthreads();
    if (threadIdx.x >= 240) return;
    int col = threadIdx.x % 40;
    int rg = (threadIdx.x / 40) * 4;
    float acc[4] = {};
#pragma unroll 8
    for (int k = 0; k < 128; ++k) {
        float w = Wl[k * 40 + col];
#pragma unroll
        for (int r = 0; r < 4; ++r)
            acc[r] = fmaf(Al[(rg + r) * 128 + k], w, acc[r]);
    }
#pragma unroll
    for (int r = 0; r < 4; ++r) {
        int row = row0 + rg + r;
        if (row < M) out[(size_t)row * 40 + col] = fmaxf(acc[r], 0.f);
    }
}

// ---------------- A[M x 40] @ W[40 x 40] -> bf16 out ----------------
__global__ __launch_bounds__(256) void mm_k40_n40(const float* __restrict__ A,
                                                  const float* __restrict__ W,
                                                  unsigned short* __restrict__ out16, int M) {
    __shared__ float Wl[1600];
    for (int i = threadIdx.x; i < 400; i += 256)
        ((float4*)Wl)[i] = ((const float4*)W)[i];
    __syncthreads();
    int idx = blockIdx.x * 256 + threadIdx.x;
    int row = idx / 40, col = idx % 40;
    if (row >= M) return;
    const float* a = A + (size_t)row * 40;
    float acc = 0.f;
#pragma unroll
    for (int k = 0; k < 40; ++k)
        acc = fmaf(a[k], Wl[k * 40 + col], acc);
    out16[idx] = f2bf(acc);
}

// ============ E-side segment-mean, 128 fp8 ch, 8-lane groups (uint4 = 16 ch/lane) ============
__global__ __launch_bounds__(256) void segred128e8(const unsigned char* __restrict__ src,
                                                   const int* __restrict__ sidx,
                                                   const int* __restrict__ off,
                                                   float* __restrict__ outf, int nDest) {
    int wave = blockIdx.x * 4 + (threadIdx.x >> 6);
    if (wave >= nDest) return;
    int lane = threadIdx.x & 63;
    int grp = lane >> 3, li = lane & 7;
    int s0 = off[wave], s1 = off[wave + 1];
    unsigned lofs = (unsigned)(li << 4);   // 16 B per lane
    vf2 a0={0,0},a1={0,0},a2={0,0},a3={0,0},a4={0,0},a5={0,0},a6={0,0},a7={0,0};
#define PROC(r) { \
    unsigned o32 = ((unsigned)(r) << 7) + lofs; \
    uint4 q = *(const uint4*)(src + o32); \
    a0 += __builtin_amdgcn_cvt_pk_f32_fp8((int)q.x, false); \
    a1 += __builtin_amdgcn_cvt_pk_f32_fp8((int)q.x, true);  \
    a2 += __builtin_amdgcn_cvt_pk_f32_fp8((int)q.y, false); \
    a3 += __builtin_amdgcn_cvt_pk_f32_fp8((int)q.y, true);  \
    a4 += __builtin_amdgcn_cvt_pk_f32_fp8((int)q.z, false); \
    a5 += __builtin_amdgcn_cvt_pk_f32_fp8((int)q.z, true);  \
    a6 += __builtin_amdgcn_cvt_pk_f32_fp8((int)q.w, false); \
    a7 += __builtin_amdgcn_cvt_pk_f32_fp8((int)q.w, true);  }
    int j = s0;
    for (; j + 16 <= s1; j += 16) {
        int base = j + grp * 2;
        int r0 = sidx[base], r1 = sidx[base + 1];
        PROC(r0); PROC(r1);
    }
    {
        int base = j + grp * 2;
        if (base < s1)     PROC(sidx[base]);
        if (base + 1 < s1) PROC(sidx[base + 1]);
    }
#undef PROC
#define RED(v) { v += __shfl_xor(v, 8); v += __shfl_xor(v, 16); v += __shfl_xor(v, 32); }
    RED(a0.x) RED(a0.y) RED(a1.x) RED(a1.y) RED(a2.x) RED(a2.y) RED(a3.x) RED(a3.y)
    RED(a4.x) RED(a4.y) RED(a5.x) RED(a5.y) RED(a6.x) RED(a6.y) RED(a7.x) RED(a7.y)
#undef RED
    int c = s1 - s0;
    float inv = 1.f / (float)(c > 0 ? c : 1);
    if (grp != 0) return;
    float* op = outf + (size_t)wave * 128 + (li << 4);
    ((float4*)op)[0] = make_float4(a0.x * inv, a0.y * inv, a1.x * inv, a1.y * inv);
    ((float4*)op)[1] = make_float4(a2.x * inv, a2.y * inv, a3.x * inv, a3.y * inv);
    ((float4*)op)[2] = make_float4(a4.x * inv, a4.y * inv, a5.x * inv, a5.y * inv);
    ((float4*)op)[3] = make_float4(a6.x * inv, a6.y * inv, a7.x * inv, a7.y * inv);
}

// ============ V-side segment-mean, 128 fp8 ch, 16-lane groups, relu+foldedBN -> fp8 ============
__global__ __launch_bounds__(256) void segred128v8(const unsigned char* __restrict__ src,
                                                   const int* __restrict__ sidx,
                                                   const int* __restrict__ off,
                                                   unsigned char* __restrict__ out8, int nDest,
                                                   const float* __restrict__ bnsc,
                                                   const float* __restrict__ bnsh) {
    int wave = blockIdx.x * 4 + (threadIdx.x >> 6);
    if (wave >= nDest) return;
    int lane = threadIdx.x & 63;
    int grp = lane >> 4, li = lane & 15;
    int s0 = off[wave], s1 = off[wave + 1];
    unsigned lofs = (unsigned)(li << 3);   // 8 B per lane
    vf2 a0 = {0.f, 0.f}, a1 = {0.f, 0.f}, a2 = {0.f, 0.f}, a3 = {0.f, 0.f};
#define PROC(r) { \
    unsigned o32 = ((unsigned)(r) << 7) + lofs; \
    uint2 uu = *(const uint2*)(src + o32); \
    a0 += __builtin_amdgcn_cvt_pk_f32_fp8((int)uu.x, false); \
    a1 += __builtin_amdgcn_cvt_pk_f32_fp8((int)uu.x, true); \
    a2 += __builtin_amdgcn_cvt_pk_f32_fp8((int)uu.y, false); \
    a3 += __builtin_amdgcn_cvt_pk_f32_fp8((int)uu.y, true); }
    int j = s0;
    for (; j + 16 <= s1; j += 16) {
        const int* ip = sidx + j + grp * 4;
        int r0 = ip[0], r1 = ip[1], r2 = ip[2], r3 = ip[3];
        PROC(r0); PROC(r1); PROC(r2); PROC(r3);
    }
    if (j < s1) {
        const int* ip = sidx + j + grp * 4;
        int base = j + grp * 4;
        if (base < s1)     PROC(ip[0]);
        if (base + 1 < s1) PROC(ip[1]);
        if (base + 2 < s1) PROC(ip[2]);
        if (base + 3 < s1) PROC(ip[3]);
    }
#undef PROC
#define RED(v) { v += __shfl_xor(v, 16); v += __shfl_xor(v, 32); }
    RED(a0.x) RED(a0.y) RED(a1.x) RED(a1.y)
    RED(a2.x) RED(a2.y) RED(a3.x) RED(a3.y)
#undef RED
    int c = s1 - s0;
    float inv = 1.f / (float)(c > 0 ? c : 1);
    if (grp != 0) return;
    int c0 = li << 3;
    float4 sA = *(const float4*)(bnsc + c0), sB = *(const float4*)(bnsc + c0 + 4);
    float4 hA = *(const float4*)(bnsh + c0), hB = *(const float4*)(bnsh + c0 + 4);
    float v0 = fmaf(fmaxf(a0.x * inv, 0.f), sA.x, hA.x);
    float v1 = fmaf(fmaxf(a0.y * inv, 0.f), sA.y, hA.y);
    float v2 = fmaf(fmaxf(a1.x * inv, 0.f), sA.z, hA.z);
    float v3 = fmaf(fmaxf(a1.y * inv, 0.f), sA.w, hA.w);
    float v4 = fmaf(fmaxf(a2.x * inv, 0.f), sB.x, hB.x);
    float v5 = fmaf(fmaxf(a2.y * inv, 0.f), sB.y, hB.y);
    float v6 = fmaf(fmaxf(a3.x * inv, 0.f), sB.z, hB.z);
    float v7 = fmaf(fmaxf(a3.y * inv, 0.f), sB.w, hB.w);
    int lo = pk8<false>(v0, v1, 0); lo = pk8<true>(v2, v3, lo);
    int hi = pk8<false>(v4, v5, 0); hi = pk8<true>(v6, v7, hi);
    *(int2*)(out8 + (size_t)wave * 128 + c0) = make_int2(lo, hi);
}

// ============ segment-mean, 40 bf16 ch + log_softmax, 16-lane groups ============
__global__ __launch_bounds__(256) void segred40ls(const unsigned short* __restrict__ src,
                                                  const int* __restrict__ sidx,
                                                  const int* __restrict__ off,
                                                  float* __restrict__ out, int nDest) {
    int wave = blockIdx.x * 4 + (threadIdx.x >> 6);
    if (wave >= nDest) return;
    int lane = threadIdx.x & 63;
    int grp = lane >> 4, li = lane & 15;
    int s0 = off[wave], s1 = off[wave + 1];
    const unsigned short* sp = src + (li << 2);   // 4 channels (8B) per lane; li>=10 reads pad
    float2 a0 = {0.f,0.f}, a1 = {0.f,0.f};
#define PROC(r) { \
    uint2 uu = *(const uint2*)(sp + (size_t)(unsigned)(r) * 40); \
    float2 t0 = bfu(uu.x), t1 = bfu(uu.y); \
    a0.x += t0.x; a0.y += t0.y; a1.x += t1.x; a1.y += t1.y; }
    int j = s0;
    for (; j + 16 <= s1; j += 16) {
        const int* ip = sidx + j + grp * 4;
        int r0 = ip[0], r1 = ip[1], r2 = ip[2], r3 = ip[3];
        PROC(r0); PROC(r1); PROC(r2); PROC(r3);
    }
    if (j < s1) {
        const int* ip = sidx + j + grp * 4;
        int base = j + grp * 4;
        if (base < s1)     PROC(ip[0]);
        if (base + 1 < s1) PROC(ip[1]);
        if (base + 2 < s1) PROC(ip[2]);
        if (base + 3 < s1) PROC(ip[3]);
    }
#undef PROC
#define RED(v) { v += __shfl_xor(v, 16); v += __shfl_xor(v, 32); }
    RED(a0.x) RED(a0.y) RED(a1.x) RED(a1.y)
#undef RED
    int c = s1 - s0;
    float inv = 1.f / (float)(c > 0 ? c : 1);
    a0.x *= inv; a0.y *= inv; a1.x *= inv; a1.y *= inv;
    bool act = li < 10;
    float mv = act ? fmaxf(fmaxf(a0.x, a0.y), fmaxf(a1.x, a1.y)) : -INFINITY;
#pragma unroll
    for (int o = 1; o < 16; o <<= 1) mv = fmaxf(mv, __shfl_xor(mv, o));
    float e = act ? (__expf(a0.x - mv) + __expf(a0.y - mv) + __expf(a1.x - mv) + __expf(a1.y - mv)) : 0.f;
#pragma unroll
    for (int o = 1; o < 16; o <<= 1) e += __shfl_xor(e, o);
    float ls = __logf(e);
    if (grp == 0 && act)
        *(float4*)(out + (size_t)wave * 40 + (li << 2)) =
            make_float4(a0.x - mv - ls, a0.y - mv - ls, a1.x - mv - ls, a1.y - mv - ls);
}

extern "C" void kernel_launch(void* const* d_in, const int* in_sizes, int n_in,
                              void* d_out, int out_size, void* d_ws, size_t ws_size,
                              hipStream_t stream) {
    const float* x    = (const float*)d_in[0];
    const int*   vids = (const int*)d_in[1];
    const int*   eids = (const int*)d_in[2];
    const float* w1a  = (const float*)d_in[3];
    const float* w1b  = (const float*)d_in[4];
    const float* w2a  = (const float*)d_in[5];
    const float* w2b  = (const float*)d_in[6];
    const float* g    = (const float*)d_in[7];
    const float* bta  = (const float*)d_in[8];
    const float* mu   = (const float*)d_in[9];
    const float* var  = (const float*)d_in[10];
    float* out = (float*)d_out;
    char*  ws  = (char*)d_ws;

    // ---- workspace layout (peak ~105.2 MB) ----
    int*            srcE = (int*)(ws);                        //  0      .. 12.8M
    int*            srcV = (int*)(ws + 12800000);             // 12.8M   .. 25.6M
    unsigned*       pkE  = (unsigned*)(ws + 25600000);        // dead after s4
    unsigned*       pkV  = (unsigned*)(ws + 38400000);        // dead after s4
    unsigned char*  xh8  = (unsigned char*)(ws + 51200000);   // V*128 fp8 = 12.8 MB
    unsigned char*  hh8  = (unsigned char*)(ws + 64000000);   // V*128 fp8 = 12.8 MB
    float*          mE   = (float*)(ws + 76800000);           // E*128 f32 = 10.24 MB
    float*          y    = (float*)(ws + 87040000);           // E*128 f32 = 10.24 MB
    unsigned char*  y28  = (unsigned char*)(ws + 97280000);   // E*128 fp8 = 2.56 MB (L2-resident)
    float*          y3   = (float*)(ws + 99840000);           // E*40 f32 = 3.2 MB
    unsigned short* y4h  = (unsigned short*)(ws + 103040000); // E*40 bf16 = 1.6 MB
    int*            offE = (int*)(ws + 104640000);            // NE+1
    int*            offV = (int*)(ws + 104720128);            // NV+1
    int*            bbE  = (int*)(ws + 105120256);            // 257
    int*            bbV  = (int*)(ws + 105122304);            // 257
    int*            gcE  = (int*)(ws + 105124352);            // 256
    int*            gcV  = (int*)(ws + 105126400);            // 256
    int*            hb   = (int*)(ws + 105128448);            // 512
    float*          bnsc = (float*)(ws + 105130496);          // 128
    float*          bnsh = (float*)(ws + 105131008);          // 128

    // ---- CSR build + x->fp8 ----
    (void)hipMemsetAsync(hb, 0, 512 * 4, stream);
    cvt_fp8<<<(NV * 16 + 255) / 256, 256, 0, stream>>>(x, xh8, NV * 16);
    s1_hist<<<NBLK, 256, 0, stream>>>(vids, eids, hb);
    s2_scan<<<1, 128, 0, stream>>>(hb, bbE, bbV, gcE, gcV, offE, offV,
                                   g, bta, mu, var, bnsc, bnsh);
    s3_bin<<<NBLK, 256, 0, stream>>>(vids, eids, gcE, gcV, pkE, pkV);
    s4_sort<<<NBE + NBV, 256, 0, stream>>>(pkE, pkV, bbE, bbV, offE, offV, srcE, srcV);

    // ---- layer 1 (mean first; matmuls on E rows) ----
    segred128e8<<<(NE + 3) / 4, 256, 0, stream>>>(xh8, srcE, offE, mE, NE);
    mm_k128_n128<true, 0><<<(NE + 31) / 32, 256, 0, stream>>>(mE, w1a, y, nullptr, NE);
    mm_k128_n128<false, 2><<<(NE + 31) / 32, 256, 0, stream>>>(y, w1b, nullptr, y28, NE);
    segred128v8<<<(NV + 3) / 4, 256, 0, stream>>>(y28, srcV, offV, hh8, NV, bnsc, bnsh);

    // ---- layer 2 (second linearity swap) ----
    segred128e8<<<(NE + 3) / 4, 256, 0, stream>>>(hh8, srcE, offE, mE, NE);
    mm_k128_n40<<<(NE + 23) / 24, 256, 0, stream>>>(mE, w2a, y3, NE);     // relu fused
    mm_k40_n40<<<(NE * 40 + 255) / 256, 256, 0, stream>>>(y3, w2b, y4h, NE);
    segred40ls<<<(NV + 3) / 4, 256, 0, stream>>>(y4h, srcV, offV, out, NV);
}